// Round 10
// baseline (3127.506 us; speedup 1.0000x reference)
//
#include <hip/hip_runtime.h>
#include <hip/hip_bf16.h>

#define BB 128
#define TT 256
#define VV 128
#define HH 1024
#define NG 4096   // 4*H gate rows (permuted: n = hu*4 + gate)
#define KK 1152   // V + H fused reduction dim
#define TVV (TT * VV)

typedef unsigned short ushort_t;
typedef short bf16x8 __attribute__((ext_vector_type(8)));
typedef float f32x4 __attribute__((ext_vector_type(4)));

__device__ __forceinline__ ushort_t f2bf(float f) {
  unsigned u = __builtin_bit_cast(unsigned, f);
  u += 0x7fffu + ((u >> 16) & 1u);   // RTNE
  return (ushort_t)(u >> 16);
}

__device__ __forceinline__ uint4 pack8(const float* p) {
  float4 a = *(const float4*)p;
  float4 b = *(const float4*)(p + 4);
  uint4 r;
  r.x = (unsigned)f2bf(a.x) | ((unsigned)f2bf(a.y) << 16);
  r.y = (unsigned)f2bf(a.z) | ((unsigned)f2bf(a.w) << 16);
  r.z = (unsigned)f2bf(b.x) | ((unsigned)f2bf(b.y) << 16);
  r.w = (unsigned)f2bf(b.z) | ((unsigned)f2bf(b.w) << 16);
  return r;
}

__device__ __forceinline__ f32x4 MFMA(bf16x8 a, bf16x8 b, f32x4 c) {
  return __builtin_amdgcn_mfma_f32_16x16x32_bf16(a, b, c, 0, 0, 0);
}

__device__ __forceinline__ float fsig(float x) {
  return 1.f / (1.f + __expf(-x));
}

// L2-bypass coherent 16B load from LLC (sc0 sc1), immediate byte offset.
#define STG(dst, base, off)                                             \
  asm volatile("global_load_dwordx4 %0, %1, off offset:" off " sc0 sc1" \
               : "=&v"(dst) : "v"(base))
#define VWAIT(n)                                          \
  asm volatile("s_waitcnt vmcnt(" #n ")" ::: "memory");   \
  __builtin_amdgcn_sched_barrier(0)
#define LGKM0                                             \
  asm volatile("s_waitcnt lgkmcnt(0)" ::: "memory");      \
  __builtin_amdgcn_sched_barrier(0)
#define RAWBAR                                            \
  __builtin_amdgcn_s_barrier();                           \
  __builtin_amdgcn_sched_barrier(0)

// ---------------- init: h0 bf16, Wl->bf16, bias = bx+bh (permuted), tags ----
__global__ void init_misc(const float* __restrict__ h_in, const float* __restrict__ Wl,
                          const float* __restrict__ bx, const float* __restrict__ bh,
                          ushort_t* __restrict__ hbf0, ushort_t* __restrict__ wlbf,
                          float* __restrict__ bias, unsigned* __restrict__ bar) {
  int i = blockIdx.x * blockDim.x + threadIdx.x;   // grid covers 131072 exactly
  hbf0[i] = f2bf(h_in[i]);
  wlbf[i] = f2bf(Wl[i]);
  if (i < NG) {
    int kg = i & 3, hc = i >> 2;
    bias[i] = bx[kg * HH + hc] + bh[kg * HH + hc];
  }
  if (i < 1056) bar[i] = 0u;
}

// ---------------- x fp32 -> bf16 once (8 elems/thread) ----------------------
__global__ void xconv(const float* __restrict__ x, ushort_t* __restrict__ xbf) {
  size_t i = (size_t)(blockIdx.x * blockDim.x + threadIdx.x) * 8;
  *(uint4*)(xbf + i) = pack8(x + i);
}

// ------------- build WcombT[n][k] bf16, n = hu*4+kg, k = [x(128) | h(1024)] --
__global__ void build_wcombT(const float* __restrict__ Wx, const float* __restrict__ Wh,
                             ushort_t* __restrict__ wcombT) {
  __shared__ float tile[32][33];
  const int k0 = blockIdx.x * 32, hc0 = blockIdx.y * 32, kg = blockIdx.z;
  const int tid = threadIdx.x;
#pragma unroll
  for (int p = 0; p < 4; ++p) {
    int kk = (tid >> 5) + p * 8, hh = tid & 31;
    int k = k0 + kk, hc = hc0 + hh;
    float v = (k < VV) ? Wx[kg * VV * HH + k * HH + hc]
                       : Wh[kg * HH * HH + (k - VV) * HH + hc];
    tile[kk][hh] = v;
  }
  __syncthreads();
#pragma unroll
  for (int p = 0; p < 4; ++p) {
    int hh = (tid >> 5) + p * 8, kk = tid & 31;
    int n = (hc0 + hh) * 4 + kg;
    wcombT[n * KK + k0 + kk] = f2bf(tile[kk][hh]);
  }
}

// ---------------- persistent LSTM: 2 blocks/CU, transposed GEMM -------------
// grid 512: mb = blk&7 (16 batch), nbk = blk>>3 (64 gate rows = 16 hu).
// Wave w owns gate rows 16w..16w+15 (144 weight VGPRs), N = 16 batch (1 tile).
// Co-resident block pairs (different mb) overlap each other's barrier waits.
__global__ __launch_bounds__(256, 2) void lstm_persist(
    const ushort_t* __restrict__ xbf, const ushort_t* __restrict__ wcombT,
    const float* __restrict__ bias, ushort_t* __restrict__ hping,
    unsigned* __restrict__ outs32, const float* __restrict__ c_in,
    float* __restrict__ hout, float* __restrict__ cout,
    unsigned* __restrict__ bar) {
  __shared__ __align__(16) ushort_t hs[16 * 1024];   // 32 KB h panel

  const int tid = threadIdx.x;
  const int mb = blockIdx.x & 7;
  const int b0 = mb * 16;
  const int nbk = blockIdx.x >> 3;                 // 0..63
  const int n0 = nbk * 64;
  const int wave = tid >> 6, lane = tid & 63;
  const int c15 = lane & 15, q = lane >> 4;
  const int bcol = b0 + c15;                       // this lane's batch col
  const int hu = nbk * 16 + wave * 4 + q;          // this lane's h-unit

  // ---- one-time: weight A-fragments (36 x 4 = 144 VGPR) ----
  bf16x8 wreg[36];
#pragma unroll
  for (int ks = 0; ks < 36; ++ks)
    wreg[ks] = *(const bf16x8*)(wcombT +
        (size_t)(n0 + wave * 16 + c15) * KK + ks * 32 + q * 8);

  const float4 biasv = *(const float4*)(bias + 4 * hu);
  float cr = c_in[(size_t)bcol * HH + hu];

  const ushort_t* xl = xbf + (size_t)bcol * TVV + q * 8;

  bf16x8 xr[4];
#pragma unroll
  for (int i = 0; i < 4; ++i)
    xr[i] = *(const bf16x8*)(xl + i * 32);

  // staging geometry: row = tid>>4 (16 batch rows), chunk col = tid&15
  const int srow = tid >> 4, scol = tid & 15;
  const ushort_t* sb0 = hping + (size_t)(b0 + srow) * HH + scol * 8;
  const ushort_t* sb1 = sb0 + (size_t)BB * HH;
  const unsigned wbase = (unsigned)srow * 2048u +
                         (((unsigned)scol * 16u) ^ (((unsigned)srow & 7u) << 4));
  // B-frag LDS addressing (panel row = c15)
  const unsigned rbase = (unsigned)c15 * 2048u;
  const unsigned swzm = ((unsigned)c15 & 7u) << 4;
  const unsigned q16x = (unsigned)q * 16u;

  unsigned* tags = bar;                            // tags[mb*64 + nbk]

  // drain prologue vmem; init acc with x-part MFMAs for t=0
  asm volatile("s_waitcnt vmcnt(0)" ::: "memory");
  __builtin_amdgcn_sched_barrier(0);

  f32x4 accE, accO;
  accE = MFMA(wreg[0], xr[0], (f32x4){0.f,0.f,0.f,0.f});
  accO = MFMA(wreg[1], xr[1], (f32x4){0.f,0.f,0.f,0.f});
  accE = MFMA(wreg[2], xr[2], accE);
  accO = MFMA(wreg[3], xr[3], accO);

#define HREAD(s) (*(const bf16x8*)((const char*)hs + \
                  (rbase + (((unsigned)(s) * 64u + q16x) ^ swzm))))

  for (int t = 0; t < TT; ++t) {
    const ushort_t* sbase = (t & 1) ? sb1 : sb0;
    ushort_t* hn_ = hping + (size_t)((t + 1) & 1) * BB * HH;

    // ---- stage h -> LDS: 8 bypass loads; counted waits; raw barriers ----
    uint4 s0,s1,s2,s3,s4,s5,s6,s7;
    __builtin_amdgcn_sched_barrier(0);
    STG(s0, sbase, "0");    STG(s1, sbase, "256");
    STG(s2, sbase, "512");  STG(s3, sbase, "768");
    STG(s4, sbase, "1024"); STG(s5, sbase, "1280");
    STG(s6, sbase, "1536"); STG(s7, sbase, "1792");
    VWAIT(4);                                      // s0..s3 arrived (k 0..511)
    *(uint4*)((char*)hs + wbase) = s0;
    *(uint4*)((char*)hs + wbase + 256) = s1;
    *(uint4*)((char*)hs + wbase + 512) = s2;
    *(uint4*)((char*)hs + wbase + 768) = s3;
    LGKM0;                                         // phase-1 writes done
    RAWBAR;                                        // slices 0..15 visible

    // ---- MFMA h slices 0..7 ----
#pragma unroll
    for (int s = 0; s < 8; ++s) {
      bf16x8 f = HREAD(s);
      if (s & 1) accO = MFMA(wreg[4 + s], f, accO);
      else       accE = MFMA(wreg[4 + s], f, accE);
    }
    VWAIT(0);                                      // s4..s7 arrived (k 512..1023)
    *(uint4*)((char*)hs + wbase + 1024) = s4;
    *(uint4*)((char*)hs + wbase + 1280) = s5;
    *(uint4*)((char*)hs + wbase + 1536) = s6;
    *(uint4*)((char*)hs + wbase + 1792) = s7;
    // ---- MFMA h slices 8..15 while phase-2 writes land ----
#pragma unroll
    for (int s = 8; s < 16; ++s) {
      bf16x8 f = HREAD(s);
      if (s & 1) accO = MFMA(wreg[4 + s], f, accO);
      else       accE = MFMA(wreg[4 + s], f, accE);
    }
    LGKM0;                                         // phase-2 writes done
    RAWBAR;                                        // slices 16..31 visible
#pragma unroll
    for (int s = 16; s < 32; ++s) {
      bf16x8 f = HREAD(s);
      if (s & 1) accO = MFMA(wreg[4 + s], f, accO);
      else       accE = MFMA(wreg[4 + s], f, accE);
    }

    // ---- pointwise: lane owns (hu, bcol); 4 gates in acc[0..3] ----
    const bool last = (t == TT - 1);
    f32x4 g = accE + accO;
    float iv = fsig(g[0] + biasv.x);
    float fv = fsig(g[1] + biasv.y);
    float gv = 2.f * fsig(2.f * (g[2] + biasv.z)) - 1.f;
    float ov = fsig(g[3] + biasv.w);
    float cn = fv * cr + iv * gv;
    cr = cn;
    float hn = ov * (2.f * fsig(cn + cn) - 1.f);
    unsigned hb = f2bf(hn), ob = f2bf(ov);
    unsigned hbp = (unsigned)__shfl_xor((int)hb, 16);   // partner hu^1
    unsigned obp = (unsigned)__shfl_xor((int)ob, 16);
    if ((q & 1) == 0) {
      if (!last)
        __hip_atomic_store((unsigned*)(hn_ + (size_t)bcol * HH + hu),
                           hb | (hbp << 16), __ATOMIC_RELAXED,
                           __HIP_MEMORY_SCOPE_AGENT);
      outs32[(((size_t)bcol * TT + t) * HH + hu) >> 1] = ob | (obp << 16);
    }
    if (last) {
      hout[(size_t)bcol * HH + hu] = hn;
      cout[(size_t)bcol * HH + hu] = cn;
    }

    if (!last) {
      __syncthreads();   // vmcnt(0): h+outs drained; all panel reads done
      if (tid == 0)
        __hip_atomic_store(tags + mb * 64 + nbk, (unsigned)(t + 1),
                           __ATOMIC_RELAXED, __HIP_MEMORY_SCOPE_AGENT);
      // ---- poll shadow: x prefetch + x MFMAs (acc re-init) ----
#pragma unroll
      for (int i = 0; i < 4; ++i)
        xr[i] = *(const bf16x8*)(xl + (t + 1) * VV + i * 32);
      accE = MFMA(wreg[0], xr[0], (f32x4){0.f,0.f,0.f,0.f});
      accO = MFMA(wreg[1], xr[1], (f32x4){0.f,0.f,0.f,0.f});
      accE = MFMA(wreg[2], xr[2], accE);
      accO = MFMA(wreg[3], xr[3], accO);
      __builtin_amdgcn_sched_barrier(0);
      // all waves poll the 64 tags of this mb group (coalesced bypass loads)
      {
        const unsigned* tg = tags + mb * 64 + lane;
        unsigned tgt = (unsigned)(t + 1);
        while (true) {
          unsigned v = __hip_atomic_load(tg, __ATOMIC_RELAXED,
                                         __HIP_MEMORY_SCOPE_AGENT);
          if (__all(v >= tgt)) break;
          __builtin_amdgcn_s_sleep(1);
        }
      }
      __builtin_amdgcn_sched_barrier(0);
    }
  }
#undef HREAD
}

// ---------------- logits = outs(bf16) @ Wl^T + bl ---------------------------
// grid 512, 256 threads (waves 2x2), WG tile 64(M) x 128(N=V)
__global__ __launch_bounds__(256) void logits_gemm(
    const ushort_t* __restrict__ outs, const ushort_t* __restrict__ wlbf,
    const float* __restrict__ bl, float* __restrict__ out) {
  __shared__ __align__(16) ushort_t Asl[2][64][72];
  __shared__ __align__(16) ushort_t Bsl[2][128][72];
  const int tid = threadIdx.x;
  const int m0 = blockIdx.x * 64;
  const int wave = tid >> 6, lane = tid & 63;
  const int wm = wave >> 1, wn = wave & 1;
  const int ar = tid >> 2, ak = (tid & 3) * 16;
  const int br = tid >> 1, bk = (tid & 1) * 32;

  f32x4 acc[2][4];
#pragma unroll
  for (int i = 0; i < 2; ++i)
#pragma unroll
    for (int j = 0; j < 4; ++j) acc[i][j] = {0.f, 0.f, 0.f, 0.f};

  const ushort_t* pa = outs + (size_t)(m0 + ar) * HH + ak;
  uint4 av0 = *(const uint4*)pa, av1 = *(const uint4*)(pa + 8);
  const ushort_t* pb = wlbf + (size_t)br * HH + bk;
  uint4 bv0 = *(const uint4*)pb, bv1 = *(const uint4*)(pb + 8);
  uint4 bv2 = *(const uint4*)(pb + 16), bv3 = *(const uint4*)(pb + 24);

  int buf = 0;
  for (int s = 0; s < 16; ++s) {
    *(uint4*)&Asl[buf][ar][ak] = av0;
    *(uint4*)&Asl[buf][ar][ak + 8] = av1;
    *(uint4*)&Bsl[buf][br][bk] = bv0;
    *(uint4*)&Bsl[buf][br][bk + 8] = bv1;
    *(uint4*)&Bsl[buf][br][bk + 16] = bv2;
    *(uint4*)&Bsl[buf][br][bk + 24] = bv3;
    if (s < 15) {
      int k0 = (s + 1) * 64;
      const ushort_t* qa = outs + (size_t)(m0 + ar) * HH + k0 + ak;
      av0 = *(const uint4*)qa; av1 = *(const uint4*)(qa + 8);
      const ushort_t* qb = wlbf + (size_t)br * HH + k0 + bk;
      bv0 = *(const uint4*)qb; bv1 = *(const uint4*)(qb + 8);
      bv2 = *(const uint4*)(qb + 16); bv3 = *(const uint4*)(qb + 24);
    }
    __syncthreads();
#pragma unroll
    for (int kk = 0; kk < 64; kk += 32) {
      int koff = kk + (lane >> 4) * 8;
      bf16x8 a0 = *(const bf16x8*)&Asl[buf][wm * 32 + (lane & 15)][koff];
      bf16x8 a1 = *(const bf16x8*)&Asl[buf][wm * 32 + 16 + (lane & 15)][koff];
      bf16x8 b0 = *(const bf16x8*)&Bsl[buf][wn * 64 + (lane & 15)][koff];
      bf16x8 b1 = *(const bf16x8*)&Bsl[buf][wn * 64 + 16 + (lane & 15)][koff];
      bf16x8 b2 = *(const bf16x8*)&Bsl[buf][wn * 64 + 32 + (lane & 15)][koff];
      bf16x8 b3 = *(const bf16x8*)&Bsl[buf][wn * 64 + 48 + (lane & 15)][koff];
      acc[0][0] = MFMA(a0, b0, acc[0][0]);
      acc[0][1] = MFMA(a0, b1, acc[0][1]);
      acc[0][2] = MFMA(a0, b2, acc[0][2]);
      acc[0][3] = MFMA(a0, b3, acc[0][3]);
      acc[1][0] = MFMA(a1, b0, acc[1][0]);
      acc[1][1] = MFMA(a1, b1, acc[1][1]);
      acc[1][2] = MFMA(a1, b2, acc[1][2]);
      acc[1][3] = MFMA(a1, b3, acc[1][3]);
    }
    buf ^= 1;
  }
#pragma unroll
  for (int i = 0; i < 2; ++i)
#pragma unroll
    for (int j = 0; j < 4; ++j)
#pragma unroll
      for (int r = 0; r < 4; ++r) {
        int m = m0 + wm * 32 + i * 16 + (lane >> 4) * 4 + r;
        int v = wn * 64 + j * 16 + (lane & 15);
        out[(size_t)m * VV + v] = acc[i][j][r] + bl[v];
      }
}

// ----------------------------------------------------------------------------
extern "C" void kernel_launch(void* const* d_in, const int* in_sizes, int n_in,
                              void* d_out, int out_size, void* d_ws, size_t ws_size,
                              hipStream_t stream) {
  const float* x    = (const float*)d_in[0];
  const float* h_in = (const float*)d_in[1];
  const float* c_in = (const float*)d_in[2];
  const float* Wx   = (const float*)d_in[3];
  const float* Wh   = (const float*)d_in[4];
  const float* bx   = (const float*)d_in[5];
  const float* bh   = (const float*)d_in[6];
  const float* Wl   = (const float*)d_in[7];
  const float* bl   = (const float*)d_in[8];

  char* ws = (char*)d_ws;
  size_t off = 0;
  ushort_t* wcombT = (ushort_t*)(ws + off); off += (size_t)NG * KK * 2;        // 9.4 MB
  ushort_t* outs   = (ushort_t*)(ws + off); off += (size_t)BB * TT * HH * 2;   // 67 MB
  ushort_t* hbf    = (ushort_t*)(ws + off); off += (size_t)2 * BB * HH * 2;    // ping-pong
  float*    bias   = (float*)(ws + off);    off += (size_t)NG * 4;
  ushort_t* wlbf   = (ushort_t*)(ws + off); off += (size_t)VV * HH * 2;
  off = (off + 127) & ~(size_t)127;
  unsigned* bar    = (unsigned*)(ws + off); off += 1056 * 4;

  float* out  = (float*)d_out;
  float* hout = out + (size_t)BB * TT * VV;
  float* cout = hout + (size_t)BB * HH;
  // xbf (8.4 MB) aliases the logits region of d_out (16.8 MB): read only by
  // lstm_persist, overwritten afterwards by logits_gemm. No ws growth.
  ushort_t* xbf = (ushort_t*)d_out;

  init_misc<<<dim3(512), dim3(256), 0, stream>>>(h_in, Wl, bx, bh,
                                                 hbf, wlbf, bias, bar);
  xconv<<<dim3(2048), dim3(256), 0, stream>>>(x, xbf);
  build_wcombT<<<dim3(36, 32, 4), dim3(256), 0, stream>>>(Wx, Wh, wcombT);

  {
    unsigned* outs32 = (unsigned*)outs;
    void* kargs[] = {(void*)&xbf, (void*)&wcombT, (void*)&bias, (void*)&hbf,
                     (void*)&outs32, (void*)&c_in, (void*)&hout, (void*)&cout,
                     (void*)&bar};
    hipError_t ce = hipLaunchCooperativeKernel((const void*)lstm_persist,
                                               dim3(512), dim3(256), kargs, 0,
                                               stream);
    if (ce != hipSuccess) {
      (void)hipGetLastError();  // clear sticky error; fall back to plain launch
      // 512 blocks, 2/CU resident by construction (LDS 32KB, VGPR<=256)
      lstm_persist<<<dim3(512), dim3(256), 0, stream>>>(
          xbf, wcombT, bias, hbf, (unsigned*)outs, c_in, hout, cout, bar);
    }
  }

  logits_gemm<<<dim3(512), dim3(256), 0, stream>>>(outs, wlbf, bl, out);
}

// Round 11
// 1272.048 us; speedup vs baseline: 2.4586x; 2.4586x over previous
//
#include <hip/hip_runtime.h>
#include <hip/hip_bf16.h>

#define BB 128
#define TT 256
#define VV 128
#define HH 1024
#define NG 4096   // 4*H gate rows (permuted: n = hu*4 + gate)
#define KK 1152   // V + H fused reduction dim
#define TVV (TT * VV)

typedef unsigned short ushort_t;
typedef short bf16x8 __attribute__((ext_vector_type(8)));
typedef float f32x4 __attribute__((ext_vector_type(4)));

__device__ __forceinline__ ushort_t f2bf(float f) {
  unsigned u = __builtin_bit_cast(unsigned, f);
  u += 0x7fffu + ((u >> 16) & 1u);   // RTNE
  return (ushort_t)(u >> 16);
}

__device__ __forceinline__ uint4 pack8(const float* p) {
  float4 a = *(const float4*)p;
  float4 b = *(const float4*)(p + 4);
  uint4 r;
  r.x = (unsigned)f2bf(a.x) | ((unsigned)f2bf(a.y) << 16);
  r.y = (unsigned)f2bf(a.z) | ((unsigned)f2bf(a.w) << 16);
  r.z = (unsigned)f2bf(b.x) | ((unsigned)f2bf(b.y) << 16);
  r.w = (unsigned)f2bf(b.z) | ((unsigned)f2bf(b.w) << 16);
  return r;
}

__device__ __forceinline__ f32x4 MFMA(bf16x8 a, bf16x8 b, f32x4 c) {
  return __builtin_amdgcn_mfma_f32_16x16x32_bf16(a, b, c, 0, 0, 0);
}

__device__ __forceinline__ float fsig(float x) {
  return 1.f / (1.f + __expf(-x));
}

// 16B loads with immediate byte offset. _C = coherent L2-bypass (sc0 sc1,
// for ping-pong h whose addresses are re-written). _N = normal cached (for
// the write-once ring: no stale-copy hazard, L2 dedups the panel per XCD).
#define STG_C(dst, base, off)                                           \
  asm volatile("global_load_dwordx4 %0, %1, off offset:" off " sc0 sc1" \
               : "=&v"(dst) : "v"(base))
#define STG_N(dst, base, off)                                           \
  asm volatile("global_load_dwordx4 %0, %1, off offset:" off            \
               : "=&v"(dst) : "v"(base))
#define VWAIT(n)                                          \
  asm volatile("s_waitcnt vmcnt(" #n ")" ::: "memory");   \
  __builtin_amdgcn_sched_barrier(0)
#define LGKM0                                             \
  asm volatile("s_waitcnt lgkmcnt(0)" ::: "memory");      \
  __builtin_amdgcn_sched_barrier(0)
#define RAWBAR                                            \
  __builtin_amdgcn_s_barrier();                           \
  __builtin_amdgcn_sched_barrier(0)

// ---------------- init: h0 bf16, Wl->bf16, bias = bx+bh (permuted), tags ----
__global__ void init_misc(const float* __restrict__ h_in, const float* __restrict__ Wl,
                          const float* __restrict__ bx, const float* __restrict__ bh,
                          ushort_t* __restrict__ hbf0, ushort_t* __restrict__ wlbf,
                          float* __restrict__ bias, unsigned* __restrict__ bar) {
  int i = blockIdx.x * blockDim.x + threadIdx.x;   // grid covers 131072 exactly
  hbf0[i] = f2bf(h_in[i]);
  wlbf[i] = f2bf(Wl[i]);
  if (i < NG) {
    int kg = i & 3, hc = i >> 2;
    bias[i] = bx[kg * HH + hc] + bh[kg * HH + hc];
  }
  if (i < 1056) bar[i] = 0u;
}

// ---------------- x fp32 -> bf16 once (8 elems/thread) ----------------------
__global__ void xconv(const float* __restrict__ x, ushort_t* __restrict__ xbf) {
  size_t i = (size_t)(blockIdx.x * blockDim.x + threadIdx.x) * 8;
  *(uint4*)(xbf + i) = pack8(x + i);
}

// ------------- build WcombT[n][k] bf16, n = hu*4+kg, k = [x(128) | h(1024)] --
__global__ void build_wcombT(const float* __restrict__ Wx, const float* __restrict__ Wh,
                             ushort_t* __restrict__ wcombT) {
  __shared__ float tile[32][33];
  const int k0 = blockIdx.x * 32, hc0 = blockIdx.y * 32, kg = blockIdx.z;
  const int tid = threadIdx.x;
#pragma unroll
  for (int p = 0; p < 4; ++p) {
    int kk = (tid >> 5) + p * 8, hh = tid & 31;
    int k = k0 + kk, hc = hc0 + hh;
    float v = (k < VV) ? Wx[kg * VV * HH + k * HH + hc]
                       : Wh[kg * HH * HH + (k - VV) * HH + hc];
    tile[kk][hh] = v;
  }
  __syncthreads();
#pragma unroll
  for (int p = 0; p < 4; ++p) {
    int hh = (tid >> 5) + p * 8, kk = tid & 31;
    int n = (hc0 + hh) * 4 + kg;
    wcombT[n * KK + k0 + kk] = f2bf(tile[kk][hh]);
  }
}

// ---------------- persistent LSTM: transposed GEMM, LDS-staged h ------------
// grid 256: mb = blk&3 (32 batch), nbk = blk>>2 (64 gate rows = 16 hu).
// Wave w owns gate rows 16w..16w+15 (144 weight regs, AGPR-backed), N = 32
// batch (2 MFMA tiles), full K. RING=true: h in a 256-slot write-once ring,
// consumers use normal cached loads (L2 dedups panel across same-XCD blocks).
template <bool RING>
__global__ __launch_bounds__(256, 1) void lstm_persist(
    const ushort_t* __restrict__ xbf, const ushort_t* __restrict__ wcombT,
    const float* __restrict__ bias, ushort_t* __restrict__ hbuf,
    unsigned* __restrict__ outs32, const float* __restrict__ c_in,
    float* __restrict__ hout, float* __restrict__ cout,
    unsigned* __restrict__ bar, int smask) {
  __shared__ __align__(16) ushort_t hs[32 * 1024];   // 64 KB h panel

  const int tid = threadIdx.x;
  const int mb = blockIdx.x & 3;
  const int b0 = mb * 32;
  const int nbk = blockIdx.x >> 2;                 // 0..63
  const int n0 = nbk * 64;
  const int wave = tid >> 6, lane = tid & 63;
  const int c15 = lane & 15, q = lane >> 4;
  const int hu = (n0 >> 2) + 4 * wave + q;         // this lane's h-unit
  const int bA = b0 + c15, bB = b0 + 16 + c15;     // batch cols (nb=0/1)

  // ---- one-time: weight A-fragments into registers (36 x 4 = 144 regs) ----
  bf16x8 wreg[36];
#pragma unroll
  for (int ks = 0; ks < 36; ++ks)
    wreg[ks] = *(const bf16x8*)(wcombT +
        (size_t)(n0 + 16 * wave + c15) * KK + ks * 32 + q * 8);

  const float4 biasv = *(const float4*)(bias + n0 + 16 * wave + 4 * q);
  float crA = c_in[(size_t)bA * HH + hu];
  float crB = c_in[(size_t)bB * HH + hu];

  const ushort_t* xlA = xbf + (size_t)bA * TVV + q * 8;
  const ushort_t* xlB = xbf + (size_t)bB * TVV + q * 8;

  bf16x8 xrA[4], xrB[4];
#pragma unroll
  for (int i = 0; i < 4; ++i) {
    xrA[i] = *(const bf16x8*)(xlA + i * 32);
    xrB[i] = *(const bf16x8*)(xlB + i * 32);
  }

  // acc chains: accA = even slices, accB = odd slices; [nb]
  f32x4 accA[2], accB[2];
  accA[0] = MFMA(wreg[0], xrA[0], (f32x4){0.f,0.f,0.f,0.f});
  accA[1] = MFMA(wreg[0], xrB[0], (f32x4){0.f,0.f,0.f,0.f});
  accB[0] = MFMA(wreg[1], xrA[1], (f32x4){0.f,0.f,0.f,0.f});
  accB[1] = MFMA(wreg[1], xrB[1], (f32x4){0.f,0.f,0.f,0.f});
  accA[0] = MFMA(wreg[2], xrA[2], accA[0]);
  accA[1] = MFMA(wreg[2], xrB[2], accA[1]);
  accB[0] = MFMA(wreg[3], xrA[3], accB[0]);
  accB[1] = MFMA(wreg[3], xrB[3], accB[1]);

  // staging geometry: thread -> row = tid>>3, 16B chunk col = tid&7 (+8p)
  const int srow = tid >> 3, scol = tid & 7;
  const size_t hstep = (size_t)BB * HH;
  const ushort_t* sb_base = hbuf + (size_t)(b0 + srow) * HH + scol * 8;
  const unsigned wb = (unsigned)srow * 2048u +
                      (((unsigned)scol * 16u) ^ (((unsigned)srow & 7u) << 4));
  // B-frag LDS addressing
  const unsigned rbase0 = (unsigned)(c15) * 2048u;
  const unsigned rbase1 = (unsigned)(16 + c15) * 2048u;
  const unsigned swzm = ((unsigned)c15 & 7u) << 4;
  const unsigned q16 = (unsigned)q * 16u;

  unsigned* tags = bar;                            // tags[mb*64 + nbk]

  for (int t = 0; t < TT; ++t) {
    const ushort_t* sbase = sb_base + (size_t)(t & smask) * hstep;
    ushort_t* hn_ = hbuf + (size_t)((t + 1) & smask) * hstep;

    // ---- stage h -> LDS: issue all 16 loads, two write phases ----
    uint4 s0,s1,s2,s3,s4,s5,s6,s7,s8,s9,s10,s11,s12,s13,s14,s15;
    __builtin_amdgcn_sched_barrier(0);
    if constexpr (RING) {
      STG_N(s0, sbase, "0");    STG_N(s1, sbase, "128");
      STG_N(s2, sbase, "256");  STG_N(s3, sbase, "384");
      STG_N(s4, sbase, "512");  STG_N(s5, sbase, "640");
      STG_N(s6, sbase, "768");  STG_N(s7, sbase, "896");
      STG_N(s8, sbase, "1024"); STG_N(s9, sbase, "1152");
      STG_N(s10, sbase, "1280"); STG_N(s11, sbase, "1408");
      STG_N(s12, sbase, "1536"); STG_N(s13, sbase, "1664");
      STG_N(s14, sbase, "1792"); STG_N(s15, sbase, "1920");
    } else {
      STG_C(s0, sbase, "0");    STG_C(s1, sbase, "128");
      STG_C(s2, sbase, "256");  STG_C(s3, sbase, "384");
      STG_C(s4, sbase, "512");  STG_C(s5, sbase, "640");
      STG_C(s6, sbase, "768");  STG_C(s7, sbase, "896");
      STG_C(s8, sbase, "1024"); STG_C(s9, sbase, "1152");
      STG_C(s10, sbase, "1280"); STG_C(s11, sbase, "1408");
      STG_C(s12, sbase, "1536"); STG_C(s13, sbase, "1664");
      STG_C(s14, sbase, "1792"); STG_C(s15, sbase, "1920");
    }
    VWAIT(8);                                      // half1 (s0..s7) ready
    *(uint4*)((char*)hs + wb) = s0;
    *(uint4*)((char*)hs + wb + 128) = s1;
    *(uint4*)((char*)hs + wb + 256) = s2;
    *(uint4*)((char*)hs + wb + 384) = s3;
    *(uint4*)((char*)hs + wb + 512) = s4;
    *(uint4*)((char*)hs + wb + 640) = s5;
    *(uint4*)((char*)hs + wb + 768) = s6;
    *(uint4*)((char*)hs + wb + 896) = s7;
    LGKM0;                                         // half1 writes done
    RAWBAR;                                        // half1 visible; half2 in flight

    // ---- MFMA h slices s=0..7 (k-cols 0..255) ----
#pragma unroll
    for (int s = 0; s < 8; ++s) {
      bf16x8 f0 = *(const bf16x8*)((const char*)hs +
                   (rbase0 + (((unsigned)s * 64u + q16) ^ swzm)));
      bf16x8 f1 = *(const bf16x8*)((const char*)hs +
                   (rbase1 + (((unsigned)s * 64u + q16) ^ swzm)));
      if (s & 1) { accB[0] = MFMA(wreg[4 + s], f0, accB[0]);
                   accB[1] = MFMA(wreg[4 + s], f1, accB[1]); }
      else       { accA[0] = MFMA(wreg[4 + s], f0, accA[0]);
                   accA[1] = MFMA(wreg[4 + s], f1, accA[1]); }
    }
    VWAIT(0);                                      // half2 (s8..s15) ready
    *(uint4*)((char*)hs + wb + 1024) = s8;
    *(uint4*)((char*)hs + wb + 1152) = s9;
    *(uint4*)((char*)hs + wb + 1280) = s10;
    *(uint4*)((char*)hs + wb + 1408) = s11;
    *(uint4*)((char*)hs + wb + 1536) = s12;
    *(uint4*)((char*)hs + wb + 1664) = s13;
    *(uint4*)((char*)hs + wb + 1792) = s14;
    *(uint4*)((char*)hs + wb + 1920) = s15;
    // ---- MFMA h slices s=8..15 while half2 writes land ----
#pragma unroll
    for (int s = 8; s < 16; ++s) {
      bf16x8 f0 = *(const bf16x8*)((const char*)hs +
                   (rbase0 + (((unsigned)s * 64u + q16) ^ swzm)));
      bf16x8 f1 = *(const bf16x8*)((const char*)hs +
                   (rbase1 + (((unsigned)s * 64u + q16) ^ swzm)));
      if (s & 1) { accB[0] = MFMA(wreg[4 + s], f0, accB[0]);
                   accB[1] = MFMA(wreg[4 + s], f1, accB[1]); }
      else       { accA[0] = MFMA(wreg[4 + s], f0, accA[0]);
                   accA[1] = MFMA(wreg[4 + s], f1, accA[1]); }
    }
    LGKM0;                                         // half2 writes done
    RAWBAR;                                        // half2 visible
#pragma unroll
    for (int s = 16; s < 32; ++s) {
      bf16x8 f0 = *(const bf16x8*)((const char*)hs +
                   (rbase0 + (((unsigned)s * 64u + q16) ^ swzm)));
      bf16x8 f1 = *(const bf16x8*)((const char*)hs +
                   (rbase1 + (((unsigned)s * 64u + q16) ^ swzm)));
      if (s & 1) { accB[0] = MFMA(wreg[4 + s], f0, accB[0]);
                   accB[1] = MFMA(wreg[4 + s], f1, accB[1]); }
      else       { accA[0] = MFMA(wreg[4 + s], f0, accA[0]);
                   accA[1] = MFMA(wreg[4 + s], f1, accA[1]); }
    }

    // ---- pointwise: 4 gates of (hu, b) live in this lane's acc[0..3] ----
    const bool last = (t == TT - 1);
    unsigned hpk[2], opk[2];
#pragma unroll
    for (int nb = 0; nb < 2; ++nb) {
      f32x4 g = (nb ? accA[1] : accA[0]) + (nb ? accB[1] : accB[0]);
      float iv = fsig(g[0] + biasv.x);
      float fv = fsig(g[1] + biasv.y);
      float gv = 2.f * fsig(2.f * (g[2] + biasv.z)) - 1.f;
      float ov = fsig(g[3] + biasv.w);
      float cold = nb ? crB : crA;
      float cn = fv * cold + iv * gv;
      if (nb) crB = cn; else crA = cn;
      float hn = ov * (2.f * fsig(cn + cn) - 1.f);
      unsigned hb = f2bf(hn), ob = f2bf(ov);
      unsigned hbp = (unsigned)__shfl_xor((int)hb, 16);
      unsigned obp = (unsigned)__shfl_xor((int)ob, 16);
      hpk[nb] = hb | (hbp << 16);
      opk[nb] = ob | (obp << 16);
      if (last) {
        int b = nb ? bB : bA;
        hout[(size_t)b * HH + hu] = hn;
        cout[(size_t)b * HH + hu] = cn;
      }
    }
    // h stores only before the barrier (they alone gate the tag)
    if (!last && (q & 1) == 0) {
      __hip_atomic_store((unsigned*)(hn_ + (size_t)bA * HH + hu), hpk[0],
                         __ATOMIC_RELAXED, __HIP_MEMORY_SCOPE_AGENT);
      __hip_atomic_store((unsigned*)(hn_ + (size_t)bB * HH + hu), hpk[1],
                         __ATOMIC_RELAXED, __HIP_MEMORY_SCOPE_AGENT);
    }

    if (!last) {
      __syncthreads();   // vmcnt(0) in every wave: h-stores at LLC
      if (tid == 0)
        __hip_atomic_store(tags + mb * 64 + nbk, (unsigned)(t + 1),
                           __ATOMIC_RELAXED, __HIP_MEMORY_SCOPE_AGENT);
      // ---- poll shadow: outs stores, x prefetch, acc re-init + x MFMA ----
      if ((q & 1) == 0) {
        outs32[(((size_t)bA * TT + t) * HH + hu) >> 1] = opk[0];
        outs32[(((size_t)bB * TT + t) * HH + hu) >> 1] = opk[1];
      }
#pragma unroll
      for (int i = 0; i < 4; ++i) {
        xrA[i] = *(const bf16x8*)(xlA + (t + 1) * VV + i * 32);
        xrB[i] = *(const bf16x8*)(xlB + (t + 1) * VV + i * 32);
      }
      accA[0] = MFMA(wreg[0], xrA[0], (f32x4){0.f,0.f,0.f,0.f});
      accA[1] = MFMA(wreg[0], xrB[0], (f32x4){0.f,0.f,0.f,0.f});
      accB[0] = MFMA(wreg[1], xrA[1], (f32x4){0.f,0.f,0.f,0.f});
      accB[1] = MFMA(wreg[1], xrB[1], (f32x4){0.f,0.f,0.f,0.f});
      accA[0] = MFMA(wreg[2], xrA[2], accA[0]);
      accA[1] = MFMA(wreg[2], xrB[2], accA[1]);
      accB[0] = MFMA(wreg[3], xrA[3], accB[0]);
      accB[1] = MFMA(wreg[3], xrB[3], accB[1]);
      // one coalesced 64-tag poll (bypass atomic loads; tags are re-written)
      if (tid < 64) {
        const unsigned* tg = tags + mb * 64 + tid;
        unsigned tgt = (unsigned)(t + 1);
        while (true) {
          unsigned v = __hip_atomic_load(tg, __ATOMIC_RELAXED,
                                         __HIP_MEMORY_SCOPE_AGENT);
          if (__all(v >= tgt)) break;
          __builtin_amdgcn_s_sleep(1);
        }
      }
      __syncthreads();
      __builtin_amdgcn_sched_barrier(0);
    } else {
      if ((q & 1) == 0) {
        outs32[(((size_t)bA * TT + t) * HH + hu) >> 1] = opk[0];
        outs32[(((size_t)bB * TT + t) * HH + hu) >> 1] = opk[1];
      }
    }
  }
}

// ---------------- logits = outs(bf16) @ Wl^T + bl ---------------------------
// grid 512, 256 threads (waves 2x2), WG tile 64(M) x 128(N=V)
__global__ __launch_bounds__(256) void logits_gemm(
    const ushort_t* __restrict__ outs, const ushort_t* __restrict__ wlbf,
    const float* __restrict__ bl, float* __restrict__ out) {
  __shared__ __align__(16) ushort_t Asl[2][64][72];
  __shared__ __align__(16) ushort_t Bsl[2][128][72];
  const int tid = threadIdx.x;
  const int m0 = blockIdx.x * 64;
  const int wave = tid >> 6, lane = tid & 63;
  const int wm = wave >> 1, wn = wave & 1;
  const int ar = tid >> 2, ak = (tid & 3) * 16;
  const int br = tid >> 1, bk = (tid & 1) * 32;

  f32x4 acc[2][4];
#pragma unroll
  for (int i = 0; i < 2; ++i)
#pragma unroll
    for (int j = 0; j < 4; ++j) acc[i][j] = {0.f, 0.f, 0.f, 0.f};

  const ushort_t* pa = outs + (size_t)(m0 + ar) * HH + ak;
  uint4 av0 = *(const uint4*)pa, av1 = *(const uint4*)(pa + 8);
  const ushort_t* pb = wlbf + (size_t)br * HH + bk;
  uint4 bv0 = *(const uint4*)pb, bv1 = *(const uint4*)(pb + 8);
  uint4 bv2 = *(const uint4*)(pb + 16), bv3 = *(const uint4*)(pb + 24);

  int buf = 0;
  for (int s = 0; s < 16; ++s) {
    *(uint4*)&Asl[buf][ar][ak] = av0;
    *(uint4*)&Asl[buf][ar][ak + 8] = av1;
    *(uint4*)&Bsl[buf][br][bk] = bv0;
    *(uint4*)&Bsl[buf][br][bk + 8] = bv1;
    *(uint4*)&Bsl[buf][br][bk + 16] = bv2;
    *(uint4*)&Bsl[buf][br][bk + 24] = bv3;
    if (s < 15) {
      int k0 = (s + 1) * 64;
      const ushort_t* qa = outs + (size_t)(m0 + ar) * HH + k0 + ak;
      av0 = *(const uint4*)qa; av1 = *(const uint4*)(qa + 8);
      const ushort_t* qb = wlbf + (size_t)br * HH + k0 + bk;
      bv0 = *(const uint4*)qb; bv1 = *(const uint4*)(qb + 8);
      bv2 = *(const uint4*)(qb + 16); bv3 = *(const uint4*)(qb + 24);
    }
    __syncthreads();
#pragma unroll
    for (int kk = 0; kk < 64; kk += 32) {
      int koff = kk + (lane >> 4) * 8;
      bf16x8 a0 = *(const bf16x8*)&Asl[buf][wm * 32 + (lane & 15)][koff];
      bf16x8 a1 = *(const bf16x8*)&Asl[buf][wm * 32 + 16 + (lane & 15)][koff];
      bf16x8 b0 = *(const bf16x8*)&Bsl[buf][wn * 64 + (lane & 15)][koff];
      bf16x8 b1 = *(const bf16x8*)&Bsl[buf][wn * 64 + 16 + (lane & 15)][koff];
      bf16x8 b2 = *(const bf16x8*)&Bsl[buf][wn * 64 + 32 + (lane & 15)][koff];
      bf16x8 b3 = *(const bf16x8*)&Bsl[buf][wn * 64 + 48 + (lane & 15)][koff];
      acc[0][0] = MFMA(a0, b0, acc[0][0]);
      acc[0][1] = MFMA(a0, b1, acc[0][1]);
      acc[0][2] = MFMA(a0, b2, acc[0][2]);
      acc[0][3] = MFMA(a0, b3, acc[0][3]);
      acc[1][0] = MFMA(a1, b0, acc[1][0]);
      acc[1][1] = MFMA(a1, b1, acc[1][1]);
      acc[1][2] = MFMA(a1, b2, acc[1][2]);
      acc[1][3] = MFMA(a1, b3, acc[1][3]);
    }
    buf ^= 1;
  }
#pragma unroll
  for (int i = 0; i < 2; ++i)
#pragma unroll
    for (int j = 0; j < 4; ++j)
#pragma unroll
      for (int r = 0; r < 4; ++r) {
        int m = m0 + wm * 32 + i * 16 + (lane >> 4) * 4 + r;
        int v = wn * 64 + j * 16 + (lane & 15);
        out[(size_t)m * VV + v] = acc[i][j][r] + bl[v];
      }
}

// ----------------------------------------------------------------------------
extern "C" void kernel_launch(void* const* d_in, const int* in_sizes, int n_in,
                              void* d_out, int out_size, void* d_ws, size_t ws_size,
                              hipStream_t stream) {
  const float* x    = (const float*)d_in[0];
  const float* h_in = (const float*)d_in[1];
  const float* c_in = (const float*)d_in[2];
  const float* Wx   = (const float*)d_in[3];
  const float* Wh   = (const float*)d_in[4];
  const float* bx   = (const float*)d_in[5];
  const float* bh   = (const float*)d_in[6];
  const float* Wl   = (const float*)d_in[7];
  const float* bl   = (const float*)d_in[8];

  const size_t hslab = (size_t)BB * HH * 2;        // 256 KB per h slot
  // ring mode needs 256 slots; fallback needs 2
  char* ws = (char*)d_ws;
  size_t off = 0;
  ushort_t* wcombT = (ushort_t*)(ws + off); off += (size_t)NG * KK * 2;        // 9.4 MB
  ushort_t* outs   = (ushort_t*)(ws + off); off += (size_t)BB * TT * HH * 2;   // 67 MB
  float*    bias   = (float*)(ws + off);    off += (size_t)NG * 4;
  ushort_t* wlbf   = (ushort_t*)(ws + off); off += (size_t)VV * HH * 2;
  off = (off + 127) & ~(size_t)127;
  unsigned* bar    = (unsigned*)(ws + off); off += 1056 * 4;
  off = (off + 255) & ~(size_t)255;
  ushort_t* hbuf   = (ushort_t*)(ws + off);
  const bool ring  = (ws_size >= off + 256 * hslab);
  // (fallback ping-pong fits in 2 slots; 77.2MB total already proven OK)

  float* out  = (float*)d_out;
  float* hout = out + (size_t)BB * TT * VV;
  float* cout = hout + (size_t)BB * HH;
  // xbf (8.4 MB) aliases the logits region of d_out (16.8 MB): read only by
  // lstm_persist, overwritten afterwards by logits_gemm. No ws growth.
  ushort_t* xbf = (ushort_t*)d_out;

  init_misc<<<dim3(512), dim3(256), 0, stream>>>(h_in, Wl, bx, bh,
                                                 hbuf, wlbf, bias, bar);
  xconv<<<dim3(2048), dim3(256), 0, stream>>>(x, xbf);
  build_wcombT<<<dim3(36, 32, 4), dim3(256), 0, stream>>>(Wx, Wh, wcombT);

  {
    unsigned* outs32 = (unsigned*)outs;
    int smask = ring ? 255 : 1;
    void* kargs[] = {(void*)&xbf, (void*)&wcombT, (void*)&bias, (void*)&hbuf,
                     (void*)&outs32, (void*)&c_in, (void*)&hout, (void*)&cout,
                     (void*)&bar, (void*)&smask};
    const void* fn = ring ? (const void*)lstm_persist<true>
                          : (const void*)lstm_persist<false>;
    hipError_t ce = hipLaunchCooperativeKernel(fn, dim3(256), dim3(256),
                                               kargs, 0, stream);
    if (ce != hipSuccess) {
      (void)hipGetLastError();  // clear sticky error; fall back to plain launch
      if (ring)
        lstm_persist<true><<<dim3(256), dim3(256), 0, stream>>>(
            xbf, wcombT, bias, hbuf, (unsigned*)outs, c_in, hout, cout, bar, 255);
      else
        lstm_persist<false><<<dim3(256), dim3(256), 0, stream>>>(
            xbf, wcombT, bias, hbuf, (unsigned*)outs, c_in, hout, cout, bar, 1);
    }
  }

  logits_gemm<<<dim3(512), dim3(256), 0, stream>>>(outs, wlbf, bl, out);
}

// Round 12
// 1044.443 us; speedup vs baseline: 2.9944x; 1.2179x over previous
//
#include <hip/hip_runtime.h>
#include <hip/hip_bf16.h>

#define BB 128
#define TT 256
#define VV 128
#define HH 1024
#define NG 4096   // 4*H gate rows (permuted: n = hu*4 + gate)
#define KK 1152   // V + H fused reduction dim
#define TVV (TT * VV)

typedef unsigned short ushort_t;
typedef short bf16x8 __attribute__((ext_vector_type(8)));
typedef float f32x4 __attribute__((ext_vector_type(4)));

__device__ __forceinline__ ushort_t f2bf(float f) {
  unsigned u = __builtin_bit_cast(unsigned, f);
  u += 0x7fffu + ((u >> 16) & 1u);   // RTNE
  return (ushort_t)(u >> 16);
}

__device__ __forceinline__ uint4 pack8(const float* p) {
  float4 a = *(const float4*)p;
  float4 b = *(const float4*)(p + 4);
  uint4 r;
  r.x = (unsigned)f2bf(a.x) | ((unsigned)f2bf(a.y) << 16);
  r.y = (unsigned)f2bf(a.z) | ((unsigned)f2bf(a.w) << 16);
  r.z = (unsigned)f2bf(b.x) | ((unsigned)f2bf(b.y) << 16);
  r.w = (unsigned)f2bf(b.z) | ((unsigned)f2bf(b.w) << 16);
  return r;
}

__device__ __forceinline__ f32x4 MFMA(bf16x8 a, bf16x8 b, f32x4 c) {
  return __builtin_amdgcn_mfma_f32_16x16x32_bf16(a, b, c, 0, 0, 0);
}

__device__ __forceinline__ float fsig(float x) {
  return 1.f / (1.f + __expf(-x));
}

// L2-bypass coherent 16B load from LLC (sc0 sc1), immediate byte offset.
#define STG(dst, base, off)                                             \
  asm volatile("global_load_dwordx4 %0, %1, off offset:" off " sc0 sc1" \
               : "=&v"(dst) : "v"(base))
#define VWAIT(n)                                          \
  asm volatile("s_waitcnt vmcnt(" #n ")" ::: "memory");   \
  __builtin_amdgcn_sched_barrier(0)
#define LGKM0                                             \
  asm volatile("s_waitcnt lgkmcnt(0)" ::: "memory");      \
  __builtin_amdgcn_sched_barrier(0)
#define RAWBAR                                            \
  __builtin_amdgcn_s_barrier();                           \
  __builtin_amdgcn_sched_barrier(0)

// ---------------- init: h0 bf16, Wl->bf16, bias = bx+bh (permuted), tags ----
__global__ void init_misc(const float* __restrict__ h_in, const float* __restrict__ Wl,
                          const float* __restrict__ bx, const float* __restrict__ bh,
                          ushort_t* __restrict__ hbf0, ushort_t* __restrict__ wlbf,
                          float* __restrict__ bias, unsigned* __restrict__ bar) {
  int i = blockIdx.x * blockDim.x + threadIdx.x;   // grid covers 131072 exactly
  hbf0[i] = f2bf(h_in[i]);
  wlbf[i] = f2bf(Wl[i]);
  if (i < NG) {
    int kg = i & 3, hc = i >> 2;
    bias[i] = bx[kg * HH + hc] + bh[kg * HH + hc];
  }
  if (i < 1056) bar[i] = 0u;
}

// ---------------- x fp32 -> bf16 once (8 elems/thread) ----------------------
__global__ void xconv(const float* __restrict__ x, ushort_t* __restrict__ xbf) {
  size_t i = (size_t)(blockIdx.x * blockDim.x + threadIdx.x) * 8;
  *(uint4*)(xbf + i) = pack8(x + i);
}

// ------------- build WcombT[n][k] bf16, n = hu*4+kg, k = [x(128) | h(1024)] --
__global__ void build_wcombT(const float* __restrict__ Wx, const float* __restrict__ Wh,
                             ushort_t* __restrict__ wcombT) {
  __shared__ float tile[32][33];
  const int k0 = blockIdx.x * 32, hc0 = blockIdx.y * 32, kg = blockIdx.z;
  const int tid = threadIdx.x;
#pragma unroll
  for (int p = 0; p < 4; ++p) {
    int kk = (tid >> 5) + p * 8, hh = tid & 31;
    int k = k0 + kk, hc = hc0 + hh;
    float v = (k < VV) ? Wx[kg * VV * HH + k * HH + hc]
                       : Wh[kg * HH * HH + (k - VV) * HH + hc];
    tile[kk][hh] = v;
  }
  __syncthreads();
#pragma unroll
  for (int p = 0; p < 4; ++p) {
    int hh = (tid >> 5) + p * 8, kk = tid & 31;
    int n = (hc0 + hh) * 4 + kg;
    wcombT[n * KK + k0 + kk] = f2bf(tile[kk][hh]);
  }
}

// ---------------- persistent LSTM: 8 waves/block (2/SIMD), weights resident -
// grid 256 x 512thr: mb = blk&3 (32 batch), nbk = blk>>2 (64 gate rows=16 hu).
// Wave (wm=wave>>1, wn=wave&1): M=16 gate rows (144 weight regs), N=16 batch.
// 2 waves/SIMD: one wave's VWAIT/poll overlaps the other's MFMAs.
__global__ __launch_bounds__(512, 1) void lstm_persist(
    const ushort_t* __restrict__ xbf, const ushort_t* __restrict__ wcombT,
    const float* __restrict__ bias, ushort_t* __restrict__ hping,
    unsigned* __restrict__ outs32, const float* __restrict__ c_in,
    float* __restrict__ hout, float* __restrict__ cout,
    unsigned* __restrict__ bar) {
  __shared__ __align__(16) ushort_t hs[32 * 1024];   // 64 KB h panel

  const int tid = threadIdx.x;
  const int mb = blockIdx.x & 3;
  const int b0 = mb * 32;
  const int nbk = blockIdx.x >> 2;                 // 0..63
  const int n0 = nbk * 64;
  const int wave = tid >> 6, lane = tid & 63;
  const int wm = wave >> 1, wn = wave & 1;
  const int c15 = lane & 15, q = lane >> 4;
  const int hu = nbk * 16 + wm * 4 + q;            // this lane's h-unit
  const int bcol = b0 + wn * 16 + c15;             // this lane's batch col

  // ---- one-time: weight A-fragments into registers (36 x 4 = 144 regs) ----
  bf16x8 wreg[36];
#pragma unroll
  for (int ks = 0; ks < 36; ++ks)
    wreg[ks] = *(const bf16x8*)(wcombT +
        (size_t)(n0 + 16 * wm + c15) * KK + ks * 32 + q * 8);

  const float4 biasv = *(const float4*)(bias + 4 * hu);
  float cr = c_in[(size_t)bcol * HH + hu];

  const ushort_t* xl = xbf + (size_t)bcol * TVV + q * 8;

  bf16x8 xr[4];
#pragma unroll
  for (int i = 0; i < 4; ++i)
    xr[i] = *(const bf16x8*)(xl + i * 32);

  // staging geometry: row = tid>>4 (32 rows), 16B chunk col = tid&15 (+256B p)
  const int srow = tid >> 4, scol = tid & 15;
  const ushort_t* sb0 = hping + (size_t)(b0 + srow) * HH + scol * 8;
  const ushort_t* sb1 = sb0 + (size_t)BB * HH;
  const unsigned wb = (unsigned)srow * 2048u +
                      (((unsigned)scol * 16u) ^ (((unsigned)srow & 7u) << 4));
  // B-frag LDS addressing (panel row = wn*16 + c15)
  const unsigned rbase = (unsigned)(wn * 16 + c15) * 2048u;
  const unsigned swzm = ((unsigned)c15 & 7u) << 4;
  const unsigned q16 = (unsigned)q * 16u;

  unsigned* tags = bar;                            // tags[mb*64 + nbk]

  // drain prologue vmem before counted-vmcnt territory
  asm volatile("s_waitcnt vmcnt(0)" ::: "memory");
  __builtin_amdgcn_sched_barrier(0);

  // acc chains (even/odd slices); x-part MFMAs for t=0
  f32x4 accE, accO;
  accE = MFMA(wreg[0], xr[0], (f32x4){0.f,0.f,0.f,0.f});
  accO = MFMA(wreg[1], xr[1], (f32x4){0.f,0.f,0.f,0.f});
  accE = MFMA(wreg[2], xr[2], accE);
  accO = MFMA(wreg[3], xr[3], accO);

#define HREAD(s) (*(const bf16x8*)((const char*)hs + \
                  (rbase + (((unsigned)(s) * 64u + q16) ^ swzm))))

  for (int t = 0; t < TT; ++t) {
    const ushort_t* sbase = (t & 1) ? sb1 : sb0;
    ushort_t* hn_ = hping + (size_t)((t + 1) & 1) * BB * HH;

    // ---- stage h -> LDS: 8 bypass loads/thread; 2 write phases ----
    uint4 s0,s1,s2,s3,s4,s5,s6,s7;
    __builtin_amdgcn_sched_barrier(0);
    STG(s0, sbase, "0");    STG(s1, sbase, "256");
    STG(s2, sbase, "512");  STG(s3, sbase, "768");
    STG(s4, sbase, "1024"); STG(s5, sbase, "1280");
    STG(s6, sbase, "1536"); STG(s7, sbase, "1792");
    VWAIT(4);                                      // p0..3 (bytes 0..1023/row)
    *(uint4*)((char*)hs + wb) = s0;
    *(uint4*)((char*)hs + wb + 256) = s1;
    *(uint4*)((char*)hs + wb + 512) = s2;
    *(uint4*)((char*)hs + wb + 768) = s3;
    LGKM0;                                         // half1 writes done
    RAWBAR;                                        // slices 0..15 visible

    // ---- MFMA h slices 0..7 ----
#pragma unroll
    for (int s = 0; s < 8; ++s) {
      bf16x8 f = HREAD(s);
      if (s & 1) accO = MFMA(wreg[4 + s], f, accO);
      else       accE = MFMA(wreg[4 + s], f, accE);
    }
    VWAIT(0);                                      // p4..7 (bytes 1024..2047)
    *(uint4*)((char*)hs + wb + 1024) = s4;
    *(uint4*)((char*)hs + wb + 1280) = s5;
    *(uint4*)((char*)hs + wb + 1536) = s6;
    *(uint4*)((char*)hs + wb + 1792) = s7;
    // ---- MFMA h slices 8..15 (half1) while half2 writes land ----
#pragma unroll
    for (int s = 8; s < 16; ++s) {
      bf16x8 f = HREAD(s);
      if (s & 1) accO = MFMA(wreg[4 + s], f, accO);
      else       accE = MFMA(wreg[4 + s], f, accE);
    }
    LGKM0;                                         // half2 writes done
    RAWBAR;                                        // slices 16..31 visible
#pragma unroll
    for (int s = 16; s < 32; ++s) {
      bf16x8 f = HREAD(s);
      if (s & 1) accO = MFMA(wreg[4 + s], f, accO);
      else       accE = MFMA(wreg[4 + s], f, accE);
    }

    // ---- pointwise: lane owns (hu, bcol); 4 gates in acc[0..3] ----
    const bool last = (t == TT - 1);
    f32x4 g = accE + accO;
    float iv = fsig(g[0] + biasv.x);
    float fv = fsig(g[1] + biasv.y);
    float gv = 2.f * fsig(2.f * (g[2] + biasv.z)) - 1.f;
    float ov = fsig(g[3] + biasv.w);
    float cn = fv * cr + iv * gv;
    cr = cn;
    float hn = ov * (2.f * fsig(cn + cn) - 1.f);
    unsigned hb = f2bf(hn), ob = f2bf(ov);
    unsigned hbp = (unsigned)__shfl_xor((int)hb, 16);   // partner hu^1
    unsigned obp = (unsigned)__shfl_xor((int)ob, 16);
    if (!last && (q & 1) == 0)
      __hip_atomic_store((unsigned*)(hn_ + (size_t)bcol * HH + hu),
                         hb | (hbp << 16), __ATOMIC_RELAXED,
                         __HIP_MEMORY_SCOPE_AGENT);
    if (last) {
      hout[(size_t)bcol * HH + hu] = hn;
      cout[(size_t)bcol * HH + hu] = cn;
    }

    if (!last) {
      __syncthreads();   // vmcnt(0) in every wave: h-stores at LLC
      if (tid == 0)
        __hip_atomic_store(tags + mb * 64 + nbk, (unsigned)(t + 1),
                           __ATOMIC_RELAXED, __HIP_MEMORY_SCOPE_AGENT);
      // ---- poll shadow: outs stores, x prefetch, acc re-init + x MFMA ----
      if ((q & 1) == 0)
        outs32[(((size_t)bcol * TT + t) * HH + hu) >> 1] = ob | (obp << 16);
#pragma unroll
      for (int i = 0; i < 4; ++i)
        xr[i] = *(const bf16x8*)(xl + (t + 1) * VV + i * 32);
      accE = MFMA(wreg[0], xr[0], (f32x4){0.f,0.f,0.f,0.f});
      accO = MFMA(wreg[1], xr[1], (f32x4){0.f,0.f,0.f,0.f});
      accE = MFMA(wreg[2], xr[2], accE);
      accO = MFMA(wreg[3], xr[3], accO);
      __builtin_amdgcn_sched_barrier(0);
      // wave 0: one coalesced 64-tag poll (bypass atomic loads)
      if (tid < 64) {
        const unsigned* tg = tags + mb * 64 + tid;
        unsigned tgt = (unsigned)(t + 1);
        while (true) {
          unsigned v = __hip_atomic_load(tg, __ATOMIC_RELAXED,
                                         __HIP_MEMORY_SCOPE_AGENT);
          if (__all(v >= tgt)) break;
          __builtin_amdgcn_s_sleep(1);
        }
      }
      __syncthreads();
      __builtin_amdgcn_sched_barrier(0);
    } else {
      if ((q & 1) == 0)
        outs32[(((size_t)bcol * TT + t) * HH + hu) >> 1] = ob | (obp << 16);
    }
  }
#undef HREAD
}

// ---------------- logits = outs(bf16) @ Wl^T + bl ---------------------------
// grid 512, 256 threads (waves 2x2), WG tile 64(M) x 128(N=V)
__global__ __launch_bounds__(256) void logits_gemm(
    const ushort_t* __restrict__ outs, const ushort_t* __restrict__ wlbf,
    const float* __restrict__ bl, float* __restrict__ out) {
  __shared__ __align__(16) ushort_t Asl[2][64][72];
  __shared__ __align__(16) ushort_t Bsl[2][128][72];
  const int tid = threadIdx.x;
  const int m0 = blockIdx.x * 64;
  const int wave = tid >> 6, lane = tid & 63;
  const int wm = wave >> 1, wn = wave & 1;
  const int ar = tid >> 2, ak = (tid & 3) * 16;
  const int br = tid >> 1, bk = (tid & 1) * 32;

  f32x4 acc[2][4];
#pragma unroll
  for (int i = 0; i < 2; ++i)
#pragma unroll
    for (int j = 0; j < 4; ++j) acc[i][j] = {0.f, 0.f, 0.f, 0.f};

  const ushort_t* pa = outs + (size_t)(m0 + ar) * HH + ak;
  uint4 av0 = *(const uint4*)pa, av1 = *(const uint4*)(pa + 8);
  const ushort_t* pb = wlbf + (size_t)br * HH + bk;
  uint4 bv0 = *(const uint4*)pb, bv1 = *(const uint4*)(pb + 8);
  uint4 bv2 = *(const uint4*)(pb + 16), bv3 = *(const uint4*)(pb + 24);

  int buf = 0;
  for (int s = 0; s < 16; ++s) {
    *(uint4*)&Asl[buf][ar][ak] = av0;
    *(uint4*)&Asl[buf][ar][ak + 8] = av1;
    *(uint4*)&Bsl[buf][br][bk] = bv0;
    *(uint4*)&Bsl[buf][br][bk + 8] = bv1;
    *(uint4*)&Bsl[buf][br][bk + 16] = bv2;
    *(uint4*)&Bsl[buf][br][bk + 24] = bv3;
    if (s < 15) {
      int k0 = (s + 1) * 64;
      const ushort_t* qa = outs + (size_t)(m0 + ar) * HH + k0 + ak;
      av0 = *(const uint4*)qa; av1 = *(const uint4*)(qa + 8);
      const ushort_t* qb = wlbf + (size_t)br * HH + k0 + bk;
      bv0 = *(const uint4*)qb; bv1 = *(const uint4*)(qb + 8);
      bv2 = *(const uint4*)(qb + 16); bv3 = *(const uint4*)(qb + 24);
    }
    __syncthreads();
#pragma unroll
    for (int kk = 0; kk < 64; kk += 32) {
      int koff = kk + (lane >> 4) * 8;
      bf16x8 a0 = *(const bf16x8*)&Asl[buf][wm * 32 + (lane & 15)][koff];
      bf16x8 a1 = *(const bf16x8*)&Asl[buf][wm * 32 + 16 + (lane & 15)][koff];
      bf16x8 b0 = *(const bf16x8*)&Bsl[buf][wn * 64 + (lane & 15)][koff];
      bf16x8 b1 = *(const bf16x8*)&Bsl[buf][wn * 64 + 16 + (lane & 15)][koff];
      bf16x8 b2 = *(const bf16x8*)&Bsl[buf][wn * 64 + 32 + (lane & 15)][koff];
      bf16x8 b3 = *(const bf16x8*)&Bsl[buf][wn * 64 + 48 + (lane & 15)][koff];
      acc[0][0] = MFMA(a0, b0, acc[0][0]);
      acc[0][1] = MFMA(a0, b1, acc[0][1]);
      acc[0][2] = MFMA(a0, b2, acc[0][2]);
      acc[0][3] = MFMA(a0, b3, acc[0][3]);
      acc[1][0] = MFMA(a1, b0, acc[1][0]);
      acc[1][1] = MFMA(a1, b1, acc[1][1]);
      acc[1][2] = MFMA(a1, b2, acc[1][2]);
      acc[1][3] = MFMA(a1, b3, acc[1][3]);
    }
    buf ^= 1;
  }
#pragma unroll
  for (int i = 0; i < 2; ++i)
#pragma unroll
    for (int j = 0; j < 4; ++j)
#pragma unroll
      for (int r = 0; r < 4; ++r) {
        int m = m0 + wm * 32 + i * 16 + (lane >> 4) * 4 + r;
        int v = wn * 64 + j * 16 + (lane & 15);
        out[(size_t)m * VV + v] = acc[i][j][r] + bl[v];
      }
}

// ----------------------------------------------------------------------------
extern "C" void kernel_launch(void* const* d_in, const int* in_sizes, int n_in,
                              void* d_out, int out_size, void* d_ws, size_t ws_size,
                              hipStream_t stream) {
  const float* x    = (const float*)d_in[0];
  const float* h_in = (const float*)d_in[1];
  const float* c_in = (const float*)d_in[2];
  const float* Wx   = (const float*)d_in[3];
  const float* Wh   = (const float*)d_in[4];
  const float* bx   = (const float*)d_in[5];
  const float* bh   = (const float*)d_in[6];
  const float* Wl   = (const float*)d_in[7];
  const float* bl   = (const float*)d_in[8];

  char* ws = (char*)d_ws;
  size_t off = 0;
  ushort_t* wcombT = (ushort_t*)(ws + off); off += (size_t)NG * KK * 2;        // 9.4 MB
  ushort_t* outs   = (ushort_t*)(ws + off); off += (size_t)BB * TT * HH * 2;   // 67 MB
  ushort_t* hbf    = (ushort_t*)(ws + off); off += (size_t)2 * BB * HH * 2;    // ping-pong
  float*    bias   = (float*)(ws + off);    off += (size_t)NG * 4;
  ushort_t* wlbf   = (ushort_t*)(ws + off); off += (size_t)VV * HH * 2;
  off = (off + 127) & ~(size_t)127;
  unsigned* bar    = (unsigned*)(ws + off); off += 1056 * 4;

  float* out  = (float*)d_out;
  float* hout = out + (size_t)BB * TT * VV;
  float* cout = hout + (size_t)BB * HH;
  // xbf (8.4 MB) aliases the logits region of d_out (16.8 MB): read only by
  // lstm_persist, overwritten afterwards by logits_gemm. No ws growth.
  ushort_t* xbf = (ushort_t*)d_out;

  init_misc<<<dim3(512), dim3(256), 0, stream>>>(h_in, Wl, bx, bh,
                                                 hbf, wlbf, bias, bar);
  xconv<<<dim3(2048), dim3(256), 0, stream>>>(x, xbf);
  build_wcombT<<<dim3(36, 32, 4), dim3(256), 0, stream>>>(Wx, Wh, wcombT);

  {
    unsigned* outs32 = (unsigned*)outs;
    void* kargs[] = {(void*)&xbf, (void*)&wcombT, (void*)&bias, (void*)&hbf,
                     (void*)&outs32, (void*)&c_in, (void*)&hout, (void*)&cout,
                     (void*)&bar};
    hipError_t ce = hipLaunchCooperativeKernel((const void*)lstm_persist,
                                               dim3(256), dim3(512), kargs, 0,
                                               stream);
    if (ce != hipSuccess) {
      (void)hipGetLastError();  // clear sticky error; fall back to plain launch
      lstm_persist<<<dim3(256), dim3(512), 0, stream>>>(
          xbf, wcombT, bias, hbf, (unsigned*)outs, c_in, hout, cout, bar);
    }
  }

  logits_gemm<<<dim3(512), dim3(256), 0, stream>>>(outs, wlbf, bl, out);
}

// Round 13
// 931.205 us; speedup vs baseline: 3.3586x; 1.1216x over previous
//
#include <hip/hip_runtime.h>
#include <hip/hip_bf16.h>

#define BB 128
#define TT 256
#define VV 128
#define HH 1024
#define NG 4096   // 4*H gate rows (permuted: n = hu*4 + gate)
#define KK 1152   // V + H fused reduction dim
#define TVV (TT * VV)

typedef unsigned short ushort_t;
typedef short bf16x8 __attribute__((ext_vector_type(8)));
typedef float f32x4 __attribute__((ext_vector_type(4)));

__device__ __forceinline__ ushort_t f2bf(float f) {
  unsigned u = __builtin_bit_cast(unsigned, f);
  u += 0x7fffu + ((u >> 16) & 1u);   // RTNE
  return (ushort_t)(u >> 16);
}

__device__ __forceinline__ uint4 pack8(const float* p) {
  float4 a = *(const float4*)p;
  float4 b = *(const float4*)(p + 4);
  uint4 r;
  r.x = (unsigned)f2bf(a.x) | ((unsigned)f2bf(a.y) << 16);
  r.y = (unsigned)f2bf(a.z) | ((unsigned)f2bf(a.w) << 16);
  r.z = (unsigned)f2bf(b.x) | ((unsigned)f2bf(b.y) << 16);
  r.w = (unsigned)f2bf(b.z) | ((unsigned)f2bf(b.w) << 16);
  return r;
}

__device__ __forceinline__ f32x4 MFMA(bf16x8 a, bf16x8 b, f32x4 c) {
  return __builtin_amdgcn_mfma_f32_16x16x32_bf16(a, b, c, 0, 0, 0);
}

__device__ __forceinline__ float fsig(float x) {
  return 1.f / (1.f + __expf(-x));
}

// L2-bypass coherent 16B load from LLC (sc0 sc1), immediate byte offset.
#define STG(dst, base, off)                                             \
  asm volatile("global_load_dwordx4 %0, %1, off offset:" off " sc0 sc1" \
               : "=&v"(dst) : "v"(base))
#define VWAIT(n)                                          \
  asm volatile("s_waitcnt vmcnt(" #n ")" ::: "memory");   \
  __builtin_amdgcn_sched_barrier(0)
#define LGKM0                                             \
  asm volatile("s_waitcnt lgkmcnt(0)" ::: "memory");      \
  __builtin_amdgcn_sched_barrier(0)
#define RAWBAR                                            \
  __builtin_amdgcn_s_barrier();                           \
  __builtin_amdgcn_sched_barrier(0)

// ---------------- init: h0 bf16, Wl->bf16, bias = bx+bh (permuted), tags ----
__global__ void init_misc(const float* __restrict__ h_in, const float* __restrict__ Wl,
                          const float* __restrict__ bx, const float* __restrict__ bh,
                          ushort_t* __restrict__ hbf0, ushort_t* __restrict__ wlbf,
                          float* __restrict__ bias, unsigned* __restrict__ bar) {
  int i = blockIdx.x * blockDim.x + threadIdx.x;   // grid covers 131072 exactly
  hbf0[i] = f2bf(h_in[i]);
  wlbf[i] = f2bf(Wl[i]);
  if (i < NG) {
    int kg = i & 3, hc = i >> 2;
    bias[i] = bx[kg * HH + hc] + bh[kg * HH + hc];
  }
  if (i < 1056) bar[i] = 0u;
}

// ---------------- x fp32 -> bf16 once (8 elems/thread) ----------------------
__global__ void xconv(const float* __restrict__ x, ushort_t* __restrict__ xbf) {
  size_t i = (size_t)(blockIdx.x * blockDim.x + threadIdx.x) * 8;
  *(uint4*)(xbf + i) = pack8(x + i);
}

// ------------- build WcombT[n][k] bf16, n = hu*4+kg, k = [x(128) | h(1024)] --
__global__ void build_wcombT(const float* __restrict__ Wx, const float* __restrict__ Wh,
                             ushort_t* __restrict__ wcombT) {
  __shared__ float tile[32][33];
  const int k0 = blockIdx.x * 32, hc0 = blockIdx.y * 32, kg = blockIdx.z;
  const int tid = threadIdx.x;
#pragma unroll
  for (int p = 0; p < 4; ++p) {
    int kk = (tid >> 5) + p * 8, hh = tid & 31;
    int k = k0 + kk, hc = hc0 + hh;
    float v = (k < VV) ? Wx[kg * VV * HH + k * HH + hc]
                       : Wh[kg * HH * HH + (k - VV) * HH + hc];
    tile[kk][hh] = v;
  }
  __syncthreads();
#pragma unroll
  for (int p = 0; p < 4; ++p) {
    int hh = (tid >> 5) + p * 8, kk = tid & 31;
    int n = (hc0 + hh) * 4 + kg;
    wcombT[n * KK + k0 + kk] = f2bf(tile[kk][hh]);
  }
}

// ---------------- persistent LSTM: 128 gate-rows x 16 batch per block -------
// grid 256 x 512thr: mb = blk&7 (16 batch -> 1 mb group per XCD),
// nbk = blk>>3 (128 gate rows = 32 hu). Wave w owns gate rows 16w..16w+15
// (144 weight regs, resident); N = 16 batch (1 tile). Panel = 32 KB (halved).
__global__ __launch_bounds__(512, 1) void lstm_persist(
    const ushort_t* __restrict__ xbf, const ushort_t* __restrict__ wcombT,
    const float* __restrict__ bias, ushort_t* __restrict__ hping,
    unsigned* __restrict__ outs32, const float* __restrict__ c_in,
    float* __restrict__ hout, float* __restrict__ cout,
    unsigned* __restrict__ bar) {
  __shared__ __align__(16) ushort_t hs[16 * 1024];   // 32 KB h panel

  const int tid = threadIdx.x;
  const int mb = blockIdx.x & 7;
  const int b0 = mb * 16;
  const int nbk = blockIdx.x >> 3;                 // 0..31
  const int n0 = nbk * 128;                        // gate-row base
  const int wave = tid >> 6, lane = tid & 63;
  const int c15 = lane & 15, q = lane >> 4;
  const int hu = nbk * 32 + wave * 4 + q;          // this lane's h-unit
  const int bcol = b0 + c15;                       // this lane's batch col

  // ---- one-time: weight A-fragments into registers (36 x 4 = 144 regs) ----
  bf16x8 wreg[36];
#pragma unroll
  for (int ks = 0; ks < 36; ++ks)
    wreg[ks] = *(const bf16x8*)(wcombT +
        (size_t)(n0 + 16 * wave + c15) * KK + ks * 32 + q * 8);

  const float4 biasv = *(const float4*)(bias + 4 * hu);
  float cr = c_in[(size_t)bcol * HH + hu];

  const ushort_t* xl = xbf + (size_t)bcol * TVV + q * 8;

  bf16x8 xr[4];
#pragma unroll
  for (int i = 0; i < 4; ++i)
    xr[i] = *(const bf16x8*)(xl + i * 32);

  // staging geometry: row = tid>>5 (16 rows), 16B chunk = tid&31 (+512B p)
  const int srow = tid >> 5, scol = tid & 31;
  const ushort_t* sb0 = hping + (size_t)(b0 + srow) * HH + scol * 8;
  const ushort_t* sb1 = sb0 + (size_t)BB * HH;
  const unsigned wb = (unsigned)srow * 2048u +
                      (((unsigned)scol * 16u) ^ (((unsigned)srow & 7u) << 4));
  // B-frag LDS addressing (panel row = c15; same rows for all waves)
  const unsigned rbase = (unsigned)c15 * 2048u;
  const unsigned swzm = ((unsigned)c15 & 7u) << 4;
  const unsigned q16 = (unsigned)q * 16u;

  unsigned* tags = bar;                            // tags[mb*32 + nbk]

  // drain prologue vmem before counted-vmcnt territory
  asm volatile("s_waitcnt vmcnt(0)" ::: "memory");
  __builtin_amdgcn_sched_barrier(0);

  // acc chains (even/odd slices); x-part MFMAs for t=0
  f32x4 accE, accO;
  accE = MFMA(wreg[0], xr[0], (f32x4){0.f,0.f,0.f,0.f});
  accO = MFMA(wreg[1], xr[1], (f32x4){0.f,0.f,0.f,0.f});
  accE = MFMA(wreg[2], xr[2], accE);
  accO = MFMA(wreg[3], xr[3], accO);

#define HREAD(s) (*(const bf16x8*)((const char*)hs + \
                  (rbase + (((unsigned)(s) * 64u + q16) ^ swzm))))

  for (int t = 0; t < TT; ++t) {
    const ushort_t* sbase = (t & 1) ? sb1 : sb0;
    ushort_t* hn_ = hping + (size_t)((t + 1) & 1) * BB * HH;

    // ---- stage h -> LDS: 4 bypass loads/thread; 2 write phases ----
    uint4 s0, s1, s2, s3;
    __builtin_amdgcn_sched_barrier(0);
    STG(s0, sbase, "0");    STG(s1, sbase, "512");
    STG(s2, sbase, "1024"); STG(s3, sbase, "1536");
    VWAIT(2);                                      // s0,s1 (bytes 0..1023/row)
    *(uint4*)((char*)hs + wb) = s0;
    *(uint4*)((char*)hs + wb + 512) = s1;
    LGKM0;                                         // half1 writes done
    RAWBAR;                                        // slices 0..15 visible

    // ---- MFMA h slices 0..15 while s2,s3 still in flight ----
#pragma unroll
    for (int s = 0; s < 16; ++s) {
      bf16x8 f = HREAD(s);
      if (s & 1) accO = MFMA(wreg[4 + s], f, accO);
      else       accE = MFMA(wreg[4 + s], f, accE);
    }
    VWAIT(0);                                      // s2,s3 (bytes 1024..2047)
    *(uint4*)((char*)hs + wb + 1024) = s2;
    *(uint4*)((char*)hs + wb + 1536) = s3;
    LGKM0;                                         // half2 writes done
    RAWBAR;                                        // slices 16..31 visible
#pragma unroll
    for (int s = 16; s < 32; ++s) {
      bf16x8 f = HREAD(s);
      if (s & 1) accO = MFMA(wreg[4 + s], f, accO);
      else       accE = MFMA(wreg[4 + s], f, accE);
    }

    // ---- pointwise: lane owns (hu, bcol); 4 gates in acc[0..3] ----
    const bool last = (t == TT - 1);
    f32x4 g = accE + accO;
    float iv = fsig(g[0] + biasv.x);
    float fv = fsig(g[1] + biasv.y);
    float gv = 2.f * fsig(2.f * (g[2] + biasv.z)) - 1.f;
    float ov = fsig(g[3] + biasv.w);
    float cn = fv * cr + iv * gv;
    cr = cn;
    float hn = ov * (2.f * fsig(cn + cn) - 1.f);
    unsigned hb = f2bf(hn), ob = f2bf(ov);
    unsigned hbp = (unsigned)__shfl_xor((int)hb, 16);   // partner hu^1
    unsigned obp = (unsigned)__shfl_xor((int)ob, 16);
    if (!last && (q & 1) == 0)
      __hip_atomic_store((unsigned*)(hn_ + (size_t)bcol * HH + hu),
                         hb | (hbp << 16), __ATOMIC_RELAXED,
                         __HIP_MEMORY_SCOPE_AGENT);
    if (last) {
      hout[(size_t)bcol * HH + hu] = hn;
      cout[(size_t)bcol * HH + hu] = cn;
    }

    if (!last) {
      __syncthreads();   // vmcnt(0) in every wave: h-stores at LLC
      if (tid == 0)
        __hip_atomic_store(tags + mb * 32 + nbk, (unsigned)(t + 1),
                           __ATOMIC_RELAXED, __HIP_MEMORY_SCOPE_AGENT);
      // ---- poll shadow: outs stores, x prefetch, acc re-init + x MFMA ----
      if ((q & 1) == 0)
        outs32[(((size_t)bcol * TT + t) * HH + hu) >> 1] = ob | (obp << 16);
#pragma unroll
      for (int i = 0; i < 4; ++i)
        xr[i] = *(const bf16x8*)(xl + (t + 1) * VV + i * 32);
      accE = MFMA(wreg[0], xr[0], (f32x4){0.f,0.f,0.f,0.f});
      accO = MFMA(wreg[1], xr[1], (f32x4){0.f,0.f,0.f,0.f});
      accE = MFMA(wreg[2], xr[2], accE);
      accO = MFMA(wreg[3], xr[3], accO);
      __builtin_amdgcn_sched_barrier(0);
      // wave 0: one coalesced 32-tag poll (each lane reads tag[lane&31])
      if (tid < 64) {
        const unsigned* tg = tags + mb * 32 + (tid & 31);
        unsigned tgt = (unsigned)(t + 1);
        while (true) {
          unsigned v = __hip_atomic_load(tg, __ATOMIC_RELAXED,
                                         __HIP_MEMORY_SCOPE_AGENT);
          if (__all(v >= tgt)) break;
          __builtin_amdgcn_s_sleep(1);
        }
      }
      __syncthreads();
      __builtin_amdgcn_sched_barrier(0);
    } else {
      if ((q & 1) == 0)
        outs32[(((size_t)bcol * TT + t) * HH + hu) >> 1] = ob | (obp << 16);
    }
  }
#undef HREAD
}

// ---------------- logits = outs(bf16) @ Wl^T + bl ---------------------------
// grid 512, 256 threads (waves 2x2), WG tile 64(M) x 128(N=V)
__global__ __launch_bounds__(256) void logits_gemm(
    const ushort_t* __restrict__ outs, const ushort_t* __restrict__ wlbf,
    const float* __restrict__ bl, float* __restrict__ out) {
  __shared__ __align__(16) ushort_t Asl[2][64][72];
  __shared__ __align__(16) ushort_t Bsl[2][128][72];
  const int tid = threadIdx.x;
  const int m0 = blockIdx.x * 64;
  const int wave = tid >> 6, lane = tid & 63;
  const int wm = wave >> 1, wn = wave & 1;
  const int ar = tid >> 2, ak = (tid & 3) * 16;
  const int br = tid >> 1, bk = (tid & 1) * 32;

  f32x4 acc[2][4];
#pragma unroll
  for (int i = 0; i < 2; ++i)
#pragma unroll
    for (int j = 0; j < 4; ++j) acc[i][j] = {0.f, 0.f, 0.f, 0.f};

  const ushort_t* pa = outs + (size_t)(m0 + ar) * HH + ak;
  uint4 av0 = *(const uint4*)pa, av1 = *(const uint4*)(pa + 8);
  const ushort_t* pb = wlbf + (size_t)br * HH + bk;
  uint4 bv0 = *(const uint4*)pb, bv1 = *(const uint4*)(pb + 8);
  uint4 bv2 = *(const uint4*)(pb + 16), bv3 = *(const uint4*)(pb + 24);

  int buf = 0;
  for (int s = 0; s < 16; ++s) {
    *(uint4*)&Asl[buf][ar][ak] = av0;
    *(uint4*)&Asl[buf][ar][ak + 8] = av1;
    *(uint4*)&Bsl[buf][br][bk] = bv0;
    *(uint4*)&Bsl[buf][br][bk + 8] = bv1;
    *(uint4*)&Bsl[buf][br][bk + 16] = bv2;
    *(uint4*)&Bsl[buf][br][bk + 24] = bv3;
    if (s < 15) {
      int k0 = (s + 1) * 64;
      const ushort_t* qa = outs + (size_t)(m0 + ar) * HH + k0 + ak;
      av0 = *(const uint4*)qa; av1 = *(const uint4*)(qa + 8);
      const ushort_t* qb = wlbf + (size_t)br * HH + k0 + bk;
      bv0 = *(const uint4*)qb; bv1 = *(const uint4*)(qb + 8);
      bv2 = *(const uint4*)(qb + 16); bv3 = *(const uint4*)(qb + 24);
    }
    __syncthreads();
#pragma unroll
    for (int kk = 0; kk < 64; kk += 32) {
      int koff = kk + (lane >> 4) * 8;
      bf16x8 a0 = *(const bf16x8*)&Asl[buf][wm * 32 + (lane & 15)][koff];
      bf16x8 a1 = *(const bf16x8*)&Asl[buf][wm * 32 + 16 + (lane & 15)][koff];
      bf16x8 b0 = *(const bf16x8*)&Bsl[buf][wn * 64 + (lane & 15)][koff];
      bf16x8 b1 = *(const bf16x8*)&Bsl[buf][wn * 64 + 16 + (lane & 15)][koff];
      bf16x8 b2 = *(const bf16x8*)&Bsl[buf][wn * 64 + 32 + (lane & 15)][koff];
      bf16x8 b3 = *(const bf16x8*)&Bsl[buf][wn * 64 + 48 + (lane & 15)][koff];
      acc[0][0] = MFMA(a0, b0, acc[0][0]);
      acc[0][1] = MFMA(a0, b1, acc[0][1]);
      acc[0][2] = MFMA(a0, b2, acc[0][2]);
      acc[0][3] = MFMA(a0, b3, acc[0][3]);
      acc[1][0] = MFMA(a1, b0, acc[1][0]);
      acc[1][1] = MFMA(a1, b1, acc[1][1]);
      acc[1][2] = MFMA(a1, b2, acc[1][2]);
      acc[1][3] = MFMA(a1, b3, acc[1][3]);
    }
    buf ^= 1;
  }
#pragma unroll
  for (int i = 0; i < 2; ++i)
#pragma unroll
    for (int j = 0; j < 4; ++j)
#pragma unroll
      for (int r = 0; r < 4; ++r) {
        int m = m0 + wm * 32 + i * 16 + (lane >> 4) * 4 + r;
        int v = wn * 64 + j * 16 + (lane & 15);
        out[(size_t)m * VV + v] = acc[i][j][r] + bl[v];
      }
}

// ----------------------------------------------------------------------------
extern "C" void kernel_launch(void* const* d_in, const int* in_sizes, int n_in,
                              void* d_out, int out_size, void* d_ws, size_t ws_size,
                              hipStream_t stream) {
  const float* x    = (const float*)d_in[0];
  const float* h_in = (const float*)d_in[1];
  const float* c_in = (const float*)d_in[2];
  const float* Wx   = (const float*)d_in[3];
  const float* Wh   = (const float*)d_in[4];
  const float* bx   = (const float*)d_in[5];
  const float* bh   = (const float*)d_in[6];
  const float* Wl   = (const float*)d_in[7];
  const float* bl   = (const float*)d_in[8];

  char* ws = (char*)d_ws;
  size_t off = 0;
  ushort_t* wcombT = (ushort_t*)(ws + off); off += (size_t)NG * KK * 2;        // 9.4 MB
  ushort_t* outs   = (ushort_t*)(ws + off); off += (size_t)BB * TT * HH * 2;   // 67 MB
  ushort_t* hbf    = (ushort_t*)(ws + off); off += (size_t)2 * BB * HH * 2;    // ping-pong
  float*    bias   = (float*)(ws + off);    off += (size_t)NG * 4;
  ushort_t* wlbf   = (ushort_t*)(ws + off); off += (size_t)VV * HH * 2;
  off = (off + 127) & ~(size_t)127;
  unsigned* bar    = (unsigned*)(ws + off); off += 1056 * 4;

  float* out  = (float*)d_out;
  float* hout = out + (size_t)BB * TT * VV;
  float* cout = hout + (size_t)BB * HH;
  // xbf (8.4 MB) aliases the logits region of d_out (16.8 MB): read only by
  // lstm_persist, overwritten afterwards by logits_gemm. No ws growth.
  ushort_t* xbf = (ushort_t*)d_out;

  init_misc<<<dim3(512), dim3(256), 0, stream>>>(h_in, Wl, bx, bh,
                                                 hbf, wlbf, bias, bar);
  xconv<<<dim3(2048), dim3(256), 0, stream>>>(x, xbf);
  build_wcombT<<<dim3(36, 32, 4), dim3(256), 0, stream>>>(Wx, Wh, wcombT);

  {
    unsigned* outs32 = (unsigned*)outs;
    void* kargs[] = {(void*)&xbf, (void*)&wcombT, (void*)&bias, (void*)&hbf,
                     (void*)&outs32, (void*)&c_in, (void*)&hout, (void*)&cout,
                     (void*)&bar};
    hipError_t ce = hipLaunchCooperativeKernel((const void*)lstm_persist,
                                               dim3(256), dim3(512), kargs, 0,
                                               stream);
    if (ce != hipSuccess) {
      (void)hipGetLastError();  // clear sticky error; fall back to plain launch
      lstm_persist<<<dim3(256), dim3(512), 0, stream>>>(
          xbf, wcombT, bias, hbf, (unsigned*)outs, c_in, hout, cout, bar);
    }
  }

  logits_gemm<<<dim3(512), dim3(256), 0, stream>>>(outs, wlbf, bl, out);
}

// Round 16
// 925.481 us; speedup vs baseline: 3.3793x; 1.0062x over previous
//
#include <hip/hip_runtime.h>
#include <hip/hip_bf16.h>

#define BB 128
#define TT 256
#define VV 128
#define HH 1024
#define NG 4096   // 4*H gate rows (permuted: n = hu*4 + gate)
#define KK 1152   // V + H fused reduction dim
#define TVV (TT * VV)

typedef unsigned short ushort_t;
typedef short bf16x8 __attribute__((ext_vector_type(8)));
typedef float f32x4 __attribute__((ext_vector_type(4)));

__device__ __forceinline__ ushort_t f2bf(float f) {
  unsigned u = __builtin_bit_cast(unsigned, f);
  u += 0x7fffu + ((u >> 16) & 1u);   // RTNE
  return (ushort_t)(u >> 16);
}

__device__ __forceinline__ uint4 pack8(const float* p) {
  float4 a = *(const float4*)p;
  float4 b = *(const float4*)(p + 4);
  uint4 r;
  r.x = (unsigned)f2bf(a.x) | ((unsigned)f2bf(a.y) << 16);
  r.y = (unsigned)f2bf(a.z) | ((unsigned)f2bf(a.w) << 16);
  r.z = (unsigned)f2bf(b.x) | ((unsigned)f2bf(b.y) << 16);
  r.w = (unsigned)f2bf(b.z) | ((unsigned)f2bf(b.w) << 16);
  return r;
}

__device__ __forceinline__ f32x4 MFMA(bf16x8 a, bf16x8 b, f32x4 c) {
  return __builtin_amdgcn_mfma_f32_16x16x32_bf16(a, b, c, 0, 0, 0);
}

__device__ __forceinline__ float fsig(float x) {
  return 1.f / (1.f + __expf(-x));
}

// L2-bypass coherent 16B load from LLC (sc0 sc1), immediate byte offset.
#define STG(dst, base, off)                                             \
  asm volatile("global_load_dwordx4 %0, %1, off offset:" off " sc0 sc1" \
               : "=&v"(dst) : "v"(base))
#define VWAIT(n)                                          \
  asm volatile("s_waitcnt vmcnt(" #n ")" ::: "memory");   \
  __builtin_amdgcn_sched_barrier(0)
#define LGKM0                                             \
  asm volatile("s_waitcnt lgkmcnt(0)" ::: "memory");      \
  __builtin_amdgcn_sched_barrier(0)
#define RAWBAR                                            \
  __builtin_amdgcn_s_barrier();                           \
  __builtin_amdgcn_sched_barrier(0)

// ---------------- init: h0 bf16, Wl->bf16, bias = bx+bh (permuted), tags ----
__global__ void init_misc(const float* __restrict__ h_in, const float* __restrict__ Wl,
                          const float* __restrict__ bx, const float* __restrict__ bh,
                          ushort_t* __restrict__ hbf0, ushort_t* __restrict__ wlbf,
                          float* __restrict__ bias, unsigned* __restrict__ bar) {
  int i = blockIdx.x * blockDim.x + threadIdx.x;   // grid covers 131072 exactly
  hbf0[i] = f2bf(h_in[i]);
  wlbf[i] = f2bf(Wl[i]);
  if (i < NG) {
    int kg = i & 3, hc = i >> 2;
    bias[i] = bx[kg * HH + hc] + bh[kg * HH + hc];
  }
  if (i < 1088) bar[i] = 0u;
}

// ---------------- x fp32 -> bf16 once (8 elems/thread) ----------------------
__global__ void xconv(const float* __restrict__ x, ushort_t* __restrict__ xbf) {
  size_t i = (size_t)(blockIdx.x * blockDim.x + threadIdx.x) * 8;
  *(uint4*)(xbf + i) = pack8(x + i);
}

// ------------- build WcombT[n][k] bf16, n = hu*4+kg, k = [x(128) | h(1024)] --
__global__ void build_wcombT(const float* __restrict__ Wx, const float* __restrict__ Wh,
                             ushort_t* __restrict__ wcombT) {
  __shared__ float tile[32][33];
  const int k0 = blockIdx.x * 32, hc0 = blockIdx.y * 32, kg = blockIdx.z;
  const int tid = threadIdx.x;
#pragma unroll
  for (int p = 0; p < 4; ++p) {
    int kk = (tid >> 5) + p * 8, hh = tid & 31;
    int k = k0 + kk, hc = hc0 + hh;
    float v = (k < VV) ? Wx[kg * VV * HH + k * HH + hc]
                       : Wh[kg * HH * HH + (k - VV) * HH + hc];
    tile[kk][hh] = v;
  }
  __syncthreads();
#pragma unroll
  for (int p = 0; p < 4; ++p) {
    int hh = (tid >> 5) + p * 8, kk = tid & 31;
    int n = (hc0 + hh) * 4 + kg;
    wcombT[n * KK + k0 + kk] = f2bf(tile[kk][hh]);
  }
}

// ---------------- persistent LSTM: 128 gate-rows x 16 batch per block -------
// grid 256 x 512thr: mb = blk&7 (16 batch), nbk = blk>>3 (128 gate rows).
// h-slice s of the panel is produced exactly by block nbk=s, and staging
// chunk p covers slices 8p..8p+7 -> staging is TAG-GATED per half: fast path
// (all 32 tags ready) is byte-identical to the proven R13 flow; else wait
// tags 0..15 -> stage chunks 0,1; tags 16..31 -> chunks 2,3 (skew absorbed).
__global__ __launch_bounds__(512, 1) void lstm_persist(
    const ushort_t* __restrict__ xbf, const ushort_t* __restrict__ wcombT,
    const float* __restrict__ bias, ushort_t* __restrict__ hping,
    unsigned* __restrict__ outs32, const float* __restrict__ c_in,
    float* __restrict__ hout, float* __restrict__ cout,
    unsigned* __restrict__ bar) {
  __shared__ __align__(16) ushort_t hs[16 * 1024];   // 32 KB h panel

  const int tid = threadIdx.x;
  const int mb = blockIdx.x & 7;
  const int b0 = mb * 16;
  const int nbk = blockIdx.x >> 3;                 // 0..31
  const int n0 = nbk * 128;                        // gate-row base
  const int wave = tid >> 6, lane = tid & 63;
  const int c15 = lane & 15, q = lane >> 4;
  const int hu = nbk * 32 + wave * 4 + q;          // this lane's h-unit
  const int bcol = b0 + c15;                       // this lane's batch col

  // ---- one-time: weight A-fragments into registers (36 x 4 = 144 regs) ----
  bf16x8 wreg[36];
#pragma unroll
  for (int ks = 0; ks < 36; ++ks)
    wreg[ks] = *(const bf16x8*)(wcombT +
        (size_t)(n0 + 16 * wave + c15) * KK + ks * 32 + q * 8);

  const float4 biasv = *(const float4*)(bias + 4 * hu);
  float cr = c_in[(size_t)bcol * HH + hu];

  const ushort_t* xl = xbf + (size_t)bcol * TVV + q * 8;

  bf16x8 xr[4];
#pragma unroll
  for (int i = 0; i < 4; ++i)
    xr[i] = *(const bf16x8*)(xl + i * 32);

  // staging geometry: row = tid>>5 (16 rows), 16B chunk = tid&31 (+512B p)
  const int srow = tid >> 5, scol = tid & 31;
  const ushort_t* sb0 = hping + (size_t)(b0 + srow) * HH + scol * 8;
  const ushort_t* sb1 = sb0 + (size_t)BB * HH;
  const unsigned wb = (unsigned)srow * 2048u +
                      (((unsigned)scol * 16u) ^ (((unsigned)srow & 7u) << 4));
  // B-frag LDS addressing (panel row = c15; same rows for all waves)
  const unsigned rbase = (unsigned)c15 * 2048u;
  const unsigned swzm = ((unsigned)c15 & 7u) << 4;
  const unsigned q16 = (unsigned)q * 16u;

  unsigned* tags = bar;                            // tags[mb*32 + nbk]

  // drain prologue vmem before counted-vmcnt territory
  asm volatile("s_waitcnt vmcnt(0)" ::: "memory");
  __builtin_amdgcn_sched_barrier(0);

  // acc chains (even/odd slices); x-part MFMAs for t=0
  f32x4 accE, accO;
  accE = MFMA(wreg[0], xr[0], (f32x4){0.f,0.f,0.f,0.f});
  accO = MFMA(wreg[1], xr[1], (f32x4){0.f,0.f,0.f,0.f});
  accE = MFMA(wreg[2], xr[2], accE);
  accO = MFMA(wreg[3], xr[3], accO);

#define HREAD(s) (*(const bf16x8*)((const char*)hs + \
                  (rbase + (((unsigned)(s) * 64u + q16) ^ swzm))))

  for (int t = 0; t < TT; ++t) {
    const ushort_t* sbase = (t & 1) ? sb1 : sb0;
    ushort_t* hn_ = hping + (size_t)((t + 1) & 1) * BB * HH;

    // ---- tag-gated staging: fast path == R13; else per-half waits ----
    uint4 s0, s1, s2, s3;
    __builtin_amdgcn_sched_barrier(0);
    bool gated = false;
    if (t > 0) {
      unsigned tgt = (unsigned)t;
      unsigned v0 = __hip_atomic_load(tags + mb * 32 + (lane & 31),
                                      __ATOMIC_RELAXED,
                                      __HIP_MEMORY_SCOPE_AGENT);
      if (!__all((int)(v0 >= tgt))) {
        gated = true;
        while (true) {       // wait producers of slices 0..15
          unsigned v = __hip_atomic_load(tags + mb * 32 + (lane & 15),
                                         __ATOMIC_RELAXED,
                                         __HIP_MEMORY_SCOPE_AGENT);
          if (__all((int)(v >= tgt))) break;
          __builtin_amdgcn_s_sleep(1);
        }
      }
    }
    STG(s0, sbase, "0");    STG(s1, sbase, "512");
    if (gated) {
      unsigned tgt = (unsigned)t;
      while (true) {         // wait producers of slices 16..31
        unsigned v = __hip_atomic_load(tags + mb * 32 + 16 + (lane & 15),
                                       __ATOMIC_RELAXED,
                                       __HIP_MEMORY_SCOPE_AGENT);
        if (__all((int)(v >= tgt))) break;
        __builtin_amdgcn_s_sleep(1);
      }
      // note: this poll's implicit vmcnt(0) drained s0,s1 -> VWAIT(2) below
      // is a safe no-op; in the fast path it is R13's exact counted wait.
    }
    STG(s2, sbase, "1024"); STG(s3, sbase, "1536");
    VWAIT(2);                                      // s0,s1 (bytes 0..1023/row)
    *(uint4*)((char*)hs + wb) = s0;
    *(uint4*)((char*)hs + wb + 512) = s1;
    LGKM0;                                         // half1 writes done
    RAWBAR;                                        // slices 0..15 visible

    // ---- MFMA h slices 0..15 while s2,s3 still in flight ----
#pragma unroll
    for (int s = 0; s < 16; ++s) {
      bf16x8 f = HREAD(s);
      if (s & 1) accO = MFMA(wreg[4 + s], f, accO);
      else       accE = MFMA(wreg[4 + s], f, accE);
    }
    VWAIT(0);                                      // s2,s3 (bytes 1024..2047)
    *(uint4*)((char*)hs + wb + 1024) = s2;
    *(uint4*)((char*)hs + wb + 1536) = s3;
    LGKM0;                                         // half2 writes done
    RAWBAR;                                        // slices 16..31 visible
#pragma unroll
    for (int s = 16; s < 32; ++s) {
      bf16x8 f = HREAD(s);
      if (s & 1) accO = MFMA(wreg[4 + s], f, accO);
      else       accE = MFMA(wreg[4 + s], f, accE);
    }

    // ---- pointwise: lane owns (hu, bcol); 4 gates in acc[0..3] ----
    const bool last = (t == TT - 1);
    f32x4 g = accE + accO;
    float iv = fsig(g[0] + biasv.x);
    float fv = fsig(g[1] + biasv.y);
    float gv = 2.f * fsig(2.f * (g[2] + biasv.z)) - 1.f;
    float ov = fsig(g[3] + biasv.w);
    float cn = fv * cr + iv * gv;
    cr = cn;
    float hn = ov * (2.f * fsig(cn + cn) - 1.f);
    unsigned hb = f2bf(hn), ob = f2bf(ov);
    unsigned hbp = (unsigned)__shfl_xor((int)hb, 16);   // partner hu^1
    unsigned obp = (unsigned)__shfl_xor((int)ob, 16);
    if (!last && (q & 1) == 0)
      __hip_atomic_store((unsigned*)(hn_ + (size_t)bcol * HH + hu),
                         hb | (hbp << 16), __ATOMIC_RELAXED,
                         __HIP_MEMORY_SCOPE_AGENT);
    if (last) {
      hout[(size_t)bcol * HH + hu] = hn;
      cout[(size_t)bcol * HH + hu] = cn;
    }

    if (!last) {
      __syncthreads();   // vmcnt(0) in every wave: h-stores at LLC; also
                         // guarantees all step-t LDS reads done before t+1
      if (tid == 0)
        __hip_atomic_store(tags + mb * 32 + nbk, (unsigned)(t + 1),
                           __ATOMIC_RELAXED, __HIP_MEMORY_SCOPE_AGENT);
      // ---- shadow work (overlaps other blocks' progress) ----
      if ((q & 1) == 0)
        outs32[(((size_t)bcol * TT + t) * HH + hu) >> 1] = ob | (obp << 16);
#pragma unroll
      for (int i = 0; i < 4; ++i)
        xr[i] = *(const bf16x8*)(xl + (t + 1) * VV + i * 32);
      accE = MFMA(wreg[0], xr[0], (f32x4){0.f,0.f,0.f,0.f});
      accO = MFMA(wreg[1], xr[1], (f32x4){0.f,0.f,0.f,0.f});
      accE = MFMA(wreg[2], xr[2], accE);
      accO = MFMA(wreg[3], xr[3], accO);
      __builtin_amdgcn_sched_barrier(0);
    } else {
      if ((q & 1) == 0)
        outs32[(((size_t)bcol * TT + t) * HH + hu) >> 1] = ob | (obp << 16);
    }
  }
#undef HREAD
}

// ---------------- logits = outs(bf16) @ Wl^T + bl ---------------------------
// grid 512, 256 threads (waves 2x2), WG tile 64(M) x 128(N=V)
__global__ __launch_bounds__(256) void logits_gemm(
    const ushort_t* __restrict__ outs, const ushort_t* __restrict__ wlbf,
    const float* __restrict__ bl, float* __restrict__ out) {
  __shared__ __align__(16) ushort_t Asl[2][64][72];
  __shared__ __align__(16) ushort_t Bsl[2][128][72];
  const int tid = threadIdx.x;
  const int m0 = blockIdx.x * 64;
  const int wave = tid >> 6, lane = tid & 63;
  const int wm = wave >> 1, wn = wave & 1;
  const int ar = tid >> 2, ak = (tid & 3) * 16;
  const int br = tid >> 1, bk = (tid & 1) * 32;

  f32x4 acc[2][4];
#pragma unroll
  for (int i = 0; i < 2; ++i)
#pragma unroll
    for (int j = 0; j < 4; ++j) acc[i][j] = {0.f, 0.f, 0.f, 0.f};

  const ushort_t* pa = outs + (size_t)(m0 + ar) * HH + ak;
  uint4 av0 = *(const uint4*)pa, av1 = *(const uint4*)(pa + 8);
  const ushort_t* pb = wlbf + (size_t)br * HH + bk;
  uint4 bv0 = *(const uint4*)pb, bv1 = *(const uint4*)(pb + 8);
  uint4 bv2 = *(const uint4*)(pb + 16), bv3 = *(const uint4*)(pb + 24);

  int buf = 0;
  for (int s = 0; s < 16; ++s) {
    *(uint4*)&Asl[buf][ar][ak] = av0;
    *(uint4*)&Asl[buf][ar][ak + 8] = av1;
    *(uint4*)&Bsl[buf][br][bk] = bv0;
    *(uint4*)&Bsl[buf][br][bk + 8] = bv1;
    *(uint4*)&Bsl[buf][br][bk + 16] = bv2;
    *(uint4*)&Bsl[buf][br][bk + 24] = bv3;
    if (s < 15) {
      int k0 = (s + 1) * 64;
      const ushort_t* qa = outs + (size_t)(m0 + ar) * HH + k0 + ak;
      av0 = *(const uint4*)qa; av1 = *(const uint4*)(qa + 8);
      const ushort_t* qb = wlbf + (size_t)br * HH + k0 + bk;
      bv0 = *(const uint4*)qb; bv1 = *(const uint4*)(qb + 8);
      bv2 = *(const uint4*)(qb + 16); bv3 = *(const uint4*)(qb + 24);
    }
    __syncthreads();
#pragma unroll
    for (int kk = 0; kk < 64; kk += 32) {
      int koff = kk + (lane >> 4) * 8;
      bf16x8 a0 = *(const bf16x8*)&Asl[buf][wm * 32 + (lane & 15)][koff];
      bf16x8 a1 = *(const bf16x8*)&Asl[buf][wm * 32 + 16 + (lane & 15)][koff];
      bf16x8 b0 = *(const bf16x8*)&Bsl[buf][wn * 64 + (lane & 15)][koff];
      bf16x8 b1 = *(const bf16x8*)&Bsl[buf][wn * 64 + 16 + (lane & 15)][koff];
      bf16x8 b2 = *(const bf16x8*)&Bsl[buf][wn * 64 + 32 + (lane & 15)][koff];
      bf16x8 b3 = *(const bf16x8*)&Bsl[buf][wn * 64 + 48 + (lane & 15)][koff];
      acc[0][0] = MFMA(a0, b0, acc[0][0]);
      acc[0][1] = MFMA(a0, b1, acc[0][1]);
      acc[0][2] = MFMA(a0, b2, acc[0][2]);
      acc[0][3] = MFMA(a0, b3, acc[0][3]);
      acc[1][0] = MFMA(a1, b0, acc[1][0]);
      acc[1][1] = MFMA(a1, b1, acc[1][1]);
      acc[1][2] = MFMA(a1, b2, acc[1][2]);
      acc[1][3] = MFMA(a1, b3, acc[1][3]);
    }
    buf ^= 1;
  }
#pragma unroll
  for (int i = 0; i < 2; ++i)
#pragma unroll
    for (int j = 0; j < 4; ++j)
#pragma unroll
      for (int r = 0; r < 4; ++r) {
        int m = m0 + wm * 32 + i * 16 + (lane >> 4) * 4 + r;
        int v = wn * 64 + j * 16 + (lane & 15);
        out[(size_t)m * VV + v] = acc[i][j][r] + bl[v];
      }
}

// ----------------------------------------------------------------------------
extern "C" void kernel_launch(void* const* d_in, const int* in_sizes, int n_in,
                              void* d_out, int out_size, void* d_ws, size_t ws_size,
                              hipStream_t stream) {
  const float* x    = (const float*)d_in[0];
  const float* h_in = (const float*)d_in[1];
  const float* c_in = (const float*)d_in[2];
  const float* Wx   = (const float*)d_in[3];
  const float* Wh   = (const float*)d_in[4];
  const float* bx   = (const float*)d_in[5];
  const float* bh   = (const float*)d_in[6];
  const float* Wl   = (const float*)d_in[7];
  const float* bl   = (const float*)d_in[8];

  char* ws = (char*)d_ws;
  size_t off = 0;
  ushort_t* wcombT = (ushort_t*)(ws + off); off += (size_t)NG * KK * 2;        // 9.4 MB
  ushort_t* outs   = (ushort_t*)(ws + off); off += (size_t)BB * TT * HH * 2;   // 67 MB
  ushort_t* hbf    = (ushort_t*)(ws + off); off += (size_t)2 * BB * HH * 2;    // ping-pong
  float*    bias   = (float*)(ws + off);    off += (size_t)NG * 4;
  ushort_t* wlbf   = (ushort_t*)(ws + off); off += (size_t)VV * HH * 2;
  off = (off + 127) & ~(size_t)127;
  unsigned* bar    = (unsigned*)(ws + off); off += 1088 * 4;

  float* out  = (float*)d_out;
  float* hout = out + (size_t)BB * TT * VV;
  float* cout = hout + (size_t)BB * HH;
  // xbf (8.4 MB) aliases the logits region of d_out (16.8 MB): read only by
  // lstm_persist, overwritten afterwards by logits_gemm. No ws growth.
  ushort_t* xbf = (ushort_t*)d_out;

  init_misc<<<dim3(512), dim3(256), 0, stream>>>(h_in, Wl, bx, bh,
                                                 hbf, wlbf, bias, bar);
  xconv<<<dim3(2048), dim3(256), 0, stream>>>(x, xbf);
  build_wcombT<<<dim3(36, 32, 4), dim3(256), 0, stream>>>(Wx, Wh, wcombT);

  {
    unsigned* outs32 = (unsigned*)outs;
    void* kargs[] = {(void*)&xbf, (void*)&wcombT, (void*)&bias, (void*)&hbf,
                     (void*)&outs32, (void*)&c_in, (void*)&hout, (void*)&cout,
                     (void*)&bar};
    hipError_t ce = hipLaunchCooperativeKernel((const void*)lstm_persist,
                                               dim3(256), dim3(512), kargs, 0,
                                               stream);
    if (ce != hipSuccess) {
      (void)hipGetLastError();  // clear sticky error; fall back to plain launch
      lstm_persist<<<dim3(256), dim3(512), 0, stream>>>(
          xbf, wcombT, bias, hbf, (unsigned*)outs, c_in, hout, cout, bar);
    }
  }

  logits_gemm<<<dim3(512), dim3(256), 0, stream>>>(outs, wlbf, bl, out);
}